// Round 7
// baseline (187.619 us; speedup 1.0000x reference)
//
#include <hip/hip_runtime.h>

typedef unsigned short u16;
typedef __attribute__((ext_vector_type(8))) short short8;   // 8 bf16 (guide §3 frag_ab)
typedef __attribute__((ext_vector_type(4))) short short4v;
typedef __attribute__((ext_vector_type(4))) float f32x4;    // frag_cd
typedef __attribute__((ext_vector_type(2))) unsigned int uint2v;

#define DEV static __device__ __forceinline__

static_assert(sizeof(short8) == 16, "short8 must be 16B");

// ---------- helpers ----------
DEV u16 f2b(float f) {                       // fp32 -> bf16, round-to-nearest-even
  union { float f; unsigned u; } a; a.f = f;
  unsigned u = a.u;
  unsigned r = (u + 0x7FFFu + ((u >> 16) & 1u)) >> 16;
  return (u16)r;
}

DEV unsigned cvt_pk_bf16(float lo, float hi) {   // {bf16(lo), bf16(hi)} packed
  unsigned r;
  asm("v_cvt_pk_bf16_f32 %0, %1, %2" : "=v"(r) : "v"(lo), "v"(hi));
  return r;
}

// MFMA via builtin: compiler manages hazards + allocates accumulators on the
// AGPR side of the gfx950 unified file (r5->r6 lesson: +18 us from this alone).
DEV f32x4 mfma16(short8 a, short8 b, f32x4 c) {
  return __builtin_amdgcn_mfma_f32_16x16x32_bf16(a, b, c, 0, 0, 0);
}

// async global->LDS, 16B per lane; LDS dest must be wave-uniform base + lane*16
DEV void gl_lds16(const u16* g, u16* l) {
  __builtin_amdgcn_global_load_lds(
      (const __attribute__((address_space(1))) void*)g,
      (__attribute__((address_space(3))) void*)l, 16, 0, 0);
}

// ---------- problem dims ----------
constexpr int Bz = 8, Nseq = 1024, Emb = 768, Hh = 8, Dh = 96;
constexpr int Mrows = Bz * Nseq;    // 8192
constexpr int K3 = 3 * Emb;         // 2304
// 768^-0.5 * log2(e): softmax done in exp2 domain (saves a mul per S element)
constexpr float QSCALE = 0.05205982021128899f;

// ---------- kernel 1: x fp32 -> bf16 ----------
__global__ __launch_bounds__(256) void k_cvt_x(const float* __restrict__ src,
                                               u16* __restrict__ dst) {
  int i = (blockIdx.x * 256 + threadIdx.x) * 4;
  float4 v = *(const float4*)(src + i);
  short4v o;
  o[0] = (short)f2b(v.x); o[1] = (short)f2b(v.y);
  o[2] = (short)f2b(v.z); o[3] = (short)f2b(v.w);
  *(short4v*)(dst + i) = o;
}

// ---------- kernel 2: transpose + cvt (+optional qkv column permutation) ----------
template <int PERM>
__global__ __launch_bounds__(256) void k_tcvt(const float* __restrict__ src,
                                              u16* __restrict__ dst, int R, int C) {
  __shared__ float t[32][33];
  int bx = blockIdx.x * 32;   // col tile in src
  int by = blockIdx.y * 32;   // row tile in src
  int c = threadIdx.x & 31, r8 = threadIdx.x >> 5;
#pragma unroll
  for (int p = 0; p < 4; ++p) {
    int r = r8 + p * 8;
    t[r][c] = src[(size_t)(by + r) * C + bx + c];
  }
  __syncthreads();
#pragma unroll
  for (int p = 0; p < 4; ++p) {
    int r = r8 + p * 8;
    int co = bx + r;           // dst row before permutation = src col
    int row = co;
    float mul = 1.f;
    if (PERM) {
      int h = co / 288, rem = co - h * 288;
      int d = rem / 3, s = rem - d * 3;
      row = s * 768 + h * 96 + d;
      if (s == 0) mul = QSCALE;
    }
    dst[(size_t)row * R + by + c] = f2b(t[c][r] * mul);
  }
}

// ---------- kernel 2b: permuted (and q-scaled) qkv bias, fp32 ----------
__global__ __launch_bounds__(256) void k_permbias(const float* __restrict__ b,
                                                  float* __restrict__ bp) {
  int co = blockIdx.x * 256 + threadIdx.x;
  if (co < 2304) {
    int h = co / 288, rem = co - h * 288, d = rem / 3, s = rem - d * 3;
    bp[s * 768 + h * 96 + d] = b[co] * (s == 0 ? QSCALE : 1.f);
  }
}

// ---------- kernel 3: GEMM  C[M][Nn] = A[M][K] * Bt[Nn][K]^T + bias ----------
// MODE 0: QKV gemm. cols<1536 -> LDS-transposed bf16 store to obf[.][2304];
//         cols>=1536 -> direct store into vT[B*H*96][1024].
// MODE 1: proj gemm, f32 direct store.
template <int MODE>
__global__ __launch_bounds__(256, 2) void k_gemm_bt(
    const u16* __restrict__ A, const u16* __restrict__ Bt,
    const float* __restrict__ bias,
    u16* __restrict__ obf, u16* __restrict__ vtb, float* __restrict__ of32,
    int Nn, int Kdim) {
  __shared__ __align__(16) u16 Al[128 * 32];
  __shared__ __align__(16) u16 Bl[128 * 32];
  __shared__ __align__(16) u16 Cst[4][32 * 88];   // epilogue transpose (MODE 0)
  int m0 = blockIdx.x * 128, n0 = blockIdx.y * 128;
  int tid = threadIdx.x;
  int w = tid >> 6, l = tid & 63, lr = l >> 4, lc = l & 15;
  int wr = w >> 1, wc = w & 1;
  f32x4 acc[4][4] = {};
  int nkt = Kdim >> 5;
  for (int kt = 0; kt < nkt; ++kt) {
    __syncthreads();
#pragma unroll
    for (int i = 0; i < 2; ++i) {
      int idx = i * 256 + tid;              // 512 chunks of 16B per matrix
      int r = idx >> 2, c8 = (idx & 3) * 8;
      gl_lds16(A + (size_t)(m0 + r) * Kdim + kt * 32 + c8, &Al[idx * 8]);
      gl_lds16(Bt + (size_t)(n0 + r) * Kdim + kt * 32 + c8, &Bl[idx * 8]);
    }
    __syncthreads();
    short8 af[4];
#pragma unroll
    for (int mi = 0; mi < 4; ++mi)
      af[mi] = *(const short8*)&Al[(wr * 64 + mi * 16 + lc) * 32 + lr * 8];
#pragma unroll
    for (int ni = 0; ni < 4; ++ni) {
      short8 bf = *(const short8*)&Bl[(wc * 64 + ni * 16 + lc) * 32 + lr * 8];
#pragma unroll
      for (int mi = 0; mi < 4; ++mi)
        acc[mi][ni] = mfma16(af[mi], bf, acc[mi][ni]);
    }
  }

  if (MODE == 0) {
    if (n0 < 1536) {
      // transposed store through per-wave LDS (coalesced 16B global stores)
      u16* Cb = &Cst[w][0];
#pragma unroll
      for (int mi2 = 0; mi2 < 2; ++mi2) {
#pragma unroll
        for (int mh = 0; mh < 2; ++mh) {
          int mi = mi2 * 2 + mh;
#pragma unroll
          for (int ni = 0; ni < 4; ++ni) {
            float bv = bias[n0 + wc * 64 + ni * 16 + lc];
#pragma unroll
            for (int r = 0; r < 4; ++r)
              Cb[(mh * 16 + lr * 4 + r) * 88 + ni * 16 + lc] =
                  f2b(acc[mi][ni][r] + bv);
          }
        }
#pragma unroll
        for (int i = 0; i < 4; ++i) {
          int idx = i * 64 + l;
          int row = idx >> 3, c8 = idx & 7;
          short8 vv = *(const short8*)&Cb[row * 88 + c8 * 8];
          int grow = m0 + wr * 64 + mi2 * 32 + row;
          int gcol = n0 + wc * 64 + c8 * 8;
          *(short8*)(obf + (size_t)grow * Nn + gcol) = vv;
        }
      }
    } else {
      // V section: write directly in vT layout [(b*8+h)*96+d][1024]
#pragma unroll
      for (int mi = 0; mi < 4; ++mi) {
#pragma unroll
        for (int ni = 0; ni < 4; ++ni) {
          int col = n0 + wc * 64 + ni * 16 + lc;
          float bv = bias[col];
          int dall = col - 1536;                       // = h*96 + d
          int row0 = m0 + wr * 64 + mi * 16 + lr * 4;  // rows 4-aligned, same b
          short4v o4;
#pragma unroll
          for (int r = 0; r < 4; ++r) o4[r] = (short)f2b(acc[mi][ni][r] + bv);
          *(short4v*)(vtb + ((size_t)(row0 >> 10) * 768 + dall) * 1024 +
                      (row0 & 1023)) = o4;
        }
      }
    }
  } else {
#pragma unroll
    for (int mi = 0; mi < 4; ++mi) {
#pragma unroll
      for (int ni = 0; ni < 4; ++ni) {
        int col = n0 + wc * 64 + ni * 16 + lc;
        float bv = bias[col];
        int row0 = m0 + wr * 64 + mi * 16 + lr * 4;
#pragma unroll
        for (int r = 0; r < 4; ++r)
          of32[(size_t)(row0 + r) * Nn + col] = acc[mi][ni][r] + bv;
      }
    }
  }
}

// ---------- kernel 4: flash attention, barrier-free (r7) ----------
// block = (qt,h,b), b fastest (XCD L2 locality). 4 waves x 32 q rows, fully
// INDEPENDENT: K/V per (b,h) = 384 KB, ~3 MB/XCD -> L2-resident, so K is NOT
// LDS-staged (m169 lesson). Each wave loads K frags straight from L2 into a
// named double-buffer (kA/kB, 2x-unrolled loop, rule #20), one kv-tile ahead.
// No __syncthreads anywhere; LDS = per-wave P buffer + epilogue transpose.
// (256,2): grid is 512 blocks = 2 blocks/CU, so cap regs at 256 not 168 --
// r4-r6's spills came from capping for an occupancy the grid can't reach.
struct AttnState {
  const u16* kln;   // per-lane K base
  const u16* vln;   // per-lane V base
  u16* Pw;          // per-wave P LDS [32][72]
  int lr, lc;
};

DEV void attn_body(int kt, const AttnState& st, const short8 (&qf)[2][3],
                   short8 (&KC)[12], short8 (&KN)[12], short8 (&va)[6],
                   float (&mrow)[2], float (&lrow)[2], f32x4 (&oacc)[2][6]) {
  const int lr = st.lr, lc = st.lc;
  // S^T = K Q^T : sacc[qi][kfr] holds S^T[k=16kfr+4lr+r][q=16qi+lc]
  f32x4 sacc[2][4] = {};
  __builtin_amdgcn_s_setprio(1);
#pragma unroll
  for (int kfr = 0; kfr < 4; ++kfr) {
#pragma unroll
    for (int kf = 0; kf < 3; ++kf) {
      sacc[0][kfr] = mfma16(KC[kfr * 3 + kf], qf[0][kf], sacc[0][kfr]);
      sacc[1][kfr] = mfma16(KC[kfr * 3 + kf], qf[1][kf], sacc[1][kfr]);
    }
  }
  __builtin_amdgcn_s_setprio(0);

  // issue V chunk1 loads (needed after PV chunk0) and next-tile K loads
  // (needed at next body's QK^T) -- both hide under softmax + PV chunk0.
  short8 vc[6];
#pragma unroll
  for (int nf = 0; nf < 6; ++nf)
    vc[nf] = *(const short8*)(st.vln + (size_t)nf * 16384 + kt * 64 + 32);
  if (kt < 15) {
#pragma unroll
    for (int kfr = 0; kfr < 4; ++kfr)
#pragma unroll
      for (int kf = 0; kf < 3; ++kf)
        KN[kfr * 3 + kf] = *(const short8*)(
            st.kln + (size_t)((kt + 1) * 64 + kfr * 16) * 2304 + kf * 32);
  }

  // online softmax (exp2 domain, deferred max THR=8), mostly in-lane
#pragma unroll
  for (int qi = 0; qi < 2; ++qi) {
    float mx = sacc[qi][0][0];
#pragma unroll
    for (int kfr = 0; kfr < 4; ++kfr)
#pragma unroll
      for (int r = 0; r < 4; ++r)
        if (kfr | r) mx = fmaxf(mx, sacc[qi][kfr][r]);
    mx = fmaxf(mx, __shfl_xor(mx, 16));
    mx = fmaxf(mx, __shfl_xor(mx, 32));
    if (__any(mx > mrow[qi] + 8.f)) {     // wave-uniform, rare after tile 0
      float nm = fmaxf(mrow[qi], mx);
      float sc = exp2f(mrow[qi] - nm);    // 0 on first tile
      mrow[qi] = nm;
      lrow[qi] *= sc;
#pragma unroll
      for (int nf = 0; nf < 6; ++nf)
#pragma unroll
        for (int r = 0; r < 4; ++r) oacc[qi][nf][r] *= sc;
    }
    float m = mrow[qi], rs = 0.f;
#pragma unroll
    for (int kfr = 0; kfr < 4; ++kfr) {
      float p0 = exp2f(sacc[qi][kfr][0] - m);
      float p1 = exp2f(sacc[qi][kfr][1] - m);
      float p2 = exp2f(sacc[qi][kfr][2] - m);
      float p3 = exp2f(sacc[qi][kfr][3] - m);
      rs += (p0 + p1) + (p2 + p3);
      uint2v pk;
      pk[0] = cvt_pk_bf16(p0, p1);
      pk[1] = cvt_pk_bf16(p2, p3);
      *(uint2v*)&st.Pw[(qi * 16 + lc) * 72 + kfr * 16 + lr * 4] = pk;
    }
    rs += __shfl_xor(rs, 16);
    rs += __shfl_xor(rs, 32);
    lrow[qi] += rs;
  }
  asm volatile("s_waitcnt lgkmcnt(0)" ::: "memory");   // P visible (own wave)

  // O^T += V^T P^T, kchunk 0
  short8 pb0 = *(const short8*)&st.Pw[lc * 72 + lr * 8];
  short8 pb1 = *(const short8*)&st.Pw[(16 + lc) * 72 + lr * 8];
  __builtin_amdgcn_s_setprio(1);
#pragma unroll
  for (int nf = 0; nf < 6; ++nf) {
    oacc[0][nf] = mfma16(va[nf], pb0, oacc[0][nf]);
    oacc[1][nf] = mfma16(va[nf], pb1, oacc[1][nf]);
  }
  __builtin_amdgcn_s_setprio(0);
  if (kt < 15) {                          // V chunk0 frags for kt+1
#pragma unroll
    for (int nf = 0; nf < 6; ++nf)
      va[nf] = *(const short8*)(st.vln + (size_t)nf * 16384 + (kt + 1) * 64);
  }
  // kchunk 1
  pb0 = *(const short8*)&st.Pw[lc * 72 + 32 + lr * 8];
  pb1 = *(const short8*)&st.Pw[(16 + lc) * 72 + 32 + lr * 8];
  __builtin_amdgcn_s_setprio(1);
#pragma unroll
  for (int nf = 0; nf < 6; ++nf) {
    oacc[0][nf] = mfma16(vc[nf], pb0, oacc[0][nf]);
    oacc[1][nf] = mfma16(vc[nf], pb1, oacc[1][nf]);
  }
  __builtin_amdgcn_s_setprio(0);
}

__global__ __launch_bounds__(256, 2) void k_attn(const u16* __restrict__ qkvp,
                                                 const u16* __restrict__ vt,
                                                 u16* __restrict__ ctx) {
  __shared__ __align__(16) u16 Pl[4][32 * 72];    // 18432 B, per-wave P
  __shared__ __align__(16) u16 Cst[4][32 * 104];  // 26624 B, epilogue transpose
  int blk = blockIdx.x;
  int b = blk & 7, h = (blk >> 3) & 7, qt = blk >> 6;
  int tid = threadIdx.x, w = tid >> 6, l = tid & 63;
  int lr = l >> 4, lc = l & 15;
  int q0 = qt * 128 + w * 32;
  const u16* qptr = qkvp + (size_t)b * 1024 * 2304 + h * 96;

  AttnState st;
  st.kln = qptr + 768 + (size_t)lc * 2304 + lr * 8;
  st.vln = vt + (size_t)(b * 768 + h * 96) * 1024 + (size_t)lc * 1024 + lr * 8;
  st.Pw = Pl[w];
  st.lr = lr; st.lc = lc;

  // Q-frags (B-operand of swapped QK^T): Q[q0+16qi+lc][32kf+8lr+j]
  short8 qf[2][3];
#pragma unroll
  for (int qi = 0; qi < 2; ++qi)
#pragma unroll
    for (int kf = 0; kf < 3; ++kf)
      qf[qi][kf] = *(const short8*)(qptr + (size_t)(q0 + qi * 16 + lc) * 2304 +
                                    kf * 32 + lr * 8);

  float mrow[2] = {-INFINITY, -INFINITY}, lrow[2] = {0.f, 0.f};
  f32x4 oacc[2][6] = {};    // O^T[d=16nf+4lr+r][q=16qi+lc]

  // prologue: K frags tile 0 + V chunk0 frags tile 0
  short8 kA[12], kB[12], va[6];
#pragma unroll
  for (int kfr = 0; kfr < 4; ++kfr)
#pragma unroll
    for (int kf = 0; kf < 3; ++kf)
      kA[kfr * 3 + kf] = *(const short8*)(st.kln + (size_t)(kfr * 16) * 2304 +
                                          kf * 32);
#pragma unroll
  for (int nf = 0; nf < 6; ++nf)
    va[nf] = *(const short8*)(st.vln + (size_t)nf * 16384);

  for (int kt2 = 0; kt2 < 16; kt2 += 2) {     // named double-buffer (rule #20)
    attn_body(kt2,     st, qf, kA, kB, va, mrow, lrow, oacc);
    attn_body(kt2 + 1, st, qf, kB, kA, va, mrow, lrow, oacc);
  }

  // epilogue: O^T -> O via per-wave LDS transpose, coalesced 16B stores
  u16* Cw = Cst[w];                           // [32][104]
  float inv[2] = {1.0f / lrow[0], 1.0f / lrow[1]};
#pragma unroll
  for (int qi = 0; qi < 2; ++qi) {
#pragma unroll
    for (int nf = 0; nf < 6; ++nf) {
      uint2v pk;
      pk[0] = cvt_pk_bf16(oacc[qi][nf][0] * inv[qi], oacc[qi][nf][1] * inv[qi]);
      pk[1] = cvt_pk_bf16(oacc[qi][nf][2] * inv[qi], oacc[qi][nf][3] * inv[qi]);
      *(uint2v*)&Cw[(qi * 16 + lc) * 104 + nf * 16 + lr * 4] = pk;
    }
  }
  asm volatile("s_waitcnt lgkmcnt(0)" ::: "memory");
  int crow0 = b * 1024 + qt * 128 + w * 32;
#pragma unroll
  for (int i = 0; i < 6; ++i) {
    int idx = i * 64 + l;                   // 32 rows x 12 chunks
    int row = idx / 12, c8 = idx % 12;
    short8 vv = *(const short8*)&Cw[row * 104 + c8 * 8];
    *(short8*)(ctx + (size_t)(crow0 + row) * 768 + h * 96 + c8 * 8) = vv;
  }
}

// ---------- launch ----------
extern "C" void kernel_launch(void* const* d_in, const int* in_sizes, int n_in,
                              void* d_out, int out_size, void* d_ws, size_t ws_size,
                              hipStream_t stream) {
  const float* x     = (const float*)d_in[0];
  const float* Wqkv  = (const float*)d_in[1];
  const float* bqkv  = (const float*)d_in[2];
  const float* Wproj = (const float*)d_in[3];
  const float* bproj = (const float*)d_in[4];
  float* out = (float*)d_out;

  char* ws = (char*)d_ws;
  u16*   xb     = (u16*)(ws);                    // 12,582,912 B (reused as ctx)
  u16*   wqkvT  = (u16*)(ws + 12582912);         //  3,538,944 B
  u16*   wprojT = (u16*)(ws + 16121856);         //  1,179,648 B
  float* bqkvp  = (float*)(ws + 17301504);       //      9,216 B
  u16*   qkvp   = (u16*)(ws + 17310720);         // 37,748,736 B (q,k cols only)
  u16*   vtb    = (u16*)(ws + 55059456);         // 12,582,912 B
  u16*   ctx    = xb;                            // xb dead after QKV GEMM

  k_cvt_x<<<6144, 256, 0, stream>>>(x, xb);
  k_tcvt<1><<<dim3(K3 / 32, Emb / 32), 256, 0, stream>>>(Wqkv, wqkvT, Emb, K3);
  k_tcvt<0><<<dim3(Emb / 32, Emb / 32), 256, 0, stream>>>(Wproj, wprojT, Emb, Emb);
  k_permbias<<<9, 256, 0, stream>>>(bqkv, bqkvp);
  k_gemm_bt<0><<<dim3(Mrows / 128, K3 / 128), 256, 0, stream>>>(
      xb, wqkvT, bqkvp, qkvp, vtb, nullptr, K3, Emb);
  k_attn<<<512, 256, 0, stream>>>(qkvp, vtb, ctx);
  k_gemm_bt<1><<<dim3(Mrows / 128, Emb / 128), 256, 0, stream>>>(
      ctx, wprojT, bproj, nullptr, nullptr, out, Emb, Emb);
}

// Round 8
// 183.417 us; speedup vs baseline: 1.0229x; 1.0229x over previous
//
#include <hip/hip_runtime.h>

typedef unsigned short u16;
typedef __attribute__((ext_vector_type(8))) short short8;   // 8 bf16 (guide §3 frag_ab)
typedef __attribute__((ext_vector_type(4))) short short4v;
typedef __attribute__((ext_vector_type(4))) float f32x4;    // frag_cd
typedef __attribute__((ext_vector_type(2))) unsigned int uint2v;

#define DEV static __device__ __forceinline__

static_assert(sizeof(short8) == 16, "short8 must be 16B");

// ---------- helpers ----------
DEV u16 f2b(float f) {                       // fp32 -> bf16, round-to-nearest-even
  union { float f; unsigned u; } a; a.f = f;
  unsigned u = a.u;
  unsigned r = (u + 0x7FFFu + ((u >> 16) & 1u)) >> 16;
  return (u16)r;
}

DEV unsigned cvt_pk_bf16(float lo, float hi) {   // {bf16(lo), bf16(hi)} packed
  unsigned r;
  asm("v_cvt_pk_bf16_f32 %0, %1, %2" : "=v"(r) : "v"(lo), "v"(hi));
  return r;
}

// MFMA via builtin: compiler manages hazards + allocates accumulators on the
// AGPR side of the gfx950 unified file (r5->r6 lesson: +18 us from this alone).
DEV f32x4 mfma16(short8 a, short8 b, f32x4 c) {
  return __builtin_amdgcn_mfma_f32_16x16x32_bf16(a, b, c, 0, 0, 0);
}

// async global->LDS, 16B per lane; LDS dest must be wave-uniform base + lane*16
DEV void gl_lds16(const u16* g, u16* l) {
  __builtin_amdgcn_global_load_lds(
      (const __attribute__((address_space(1))) void*)g,
      (__attribute__((address_space(3))) void*)l, 16, 0, 0);
}

// ---------- problem dims ----------
constexpr int Bz = 8, Nseq = 1024, Emb = 768, Hh = 8, Dh = 96;
constexpr int Mrows = Bz * Nseq;    // 8192
constexpr int K3 = 3 * Emb;         // 2304
// 768^-0.5 * log2(e): softmax done in exp2 domain (saves a mul per S element)
constexpr float QSCALE = 0.05205982021128899f;

// ---------- kernel 1: x fp32 -> bf16 ----------
__global__ __launch_bounds__(256) void k_cvt_x(const float* __restrict__ src,
                                               u16* __restrict__ dst) {
  int i = (blockIdx.x * 256 + threadIdx.x) * 4;
  float4 v = *(const float4*)(src + i);
  short4v o;
  o[0] = (short)f2b(v.x); o[1] = (short)f2b(v.y);
  o[2] = (short)f2b(v.z); o[3] = (short)f2b(v.w);
  *(short4v*)(dst + i) = o;
}

// ---------- kernel 2: transpose + cvt (+optional qkv column permutation) ----------
template <int PERM>
__global__ __launch_bounds__(256) void k_tcvt(const float* __restrict__ src,
                                              u16* __restrict__ dst, int R, int C) {
  __shared__ float t[32][33];
  int bx = blockIdx.x * 32;   // col tile in src
  int by = blockIdx.y * 32;   // row tile in src
  int c = threadIdx.x & 31, r8 = threadIdx.x >> 5;
#pragma unroll
  for (int p = 0; p < 4; ++p) {
    int r = r8 + p * 8;
    t[r][c] = src[(size_t)(by + r) * C + bx + c];
  }
  __syncthreads();
#pragma unroll
  for (int p = 0; p < 4; ++p) {
    int r = r8 + p * 8;
    int co = bx + r;           // dst row before permutation = src col
    int row = co;
    float mul = 1.f;
    if (PERM) {
      int h = co / 288, rem = co - h * 288;
      int d = rem / 3, s = rem - d * 3;
      row = s * 768 + h * 96 + d;
      if (s == 0) mul = QSCALE;
    }
    dst[(size_t)row * R + by + c] = f2b(t[c][r] * mul);
  }
}

// ---------- kernel 2b: permuted (and q-scaled) qkv bias, fp32 ----------
__global__ __launch_bounds__(256) void k_permbias(const float* __restrict__ b,
                                                  float* __restrict__ bp) {
  int co = blockIdx.x * 256 + threadIdx.x;
  if (co < 2304) {
    int h = co / 288, rem = co - h * 288, d = rem / 3, s = rem - d * 3;
    bp[s * 768 + h * 96 + d] = b[co] * (s == 0 ? QSCALE : 1.f);
  }
}

// ---------- kernel 3: GEMM  C[M][Nn] = A[M][K] * Bt[Nn][K]^T + bias ----------
// MODE 0: QKV gemm. cols<1536 -> LDS-transposed bf16 store to obf[.][2304];
//         cols>=1536 -> direct store into vT[B*H*96][1024].
// MODE 1: proj gemm, f32 direct store.
template <int MODE>
__global__ __launch_bounds__(256, 2) void k_gemm_bt(
    const u16* __restrict__ A, const u16* __restrict__ Bt,
    const float* __restrict__ bias,
    u16* __restrict__ obf, u16* __restrict__ vtb, float* __restrict__ of32,
    int Nn, int Kdim) {
  __shared__ __align__(16) u16 Al[128 * 32];
  __shared__ __align__(16) u16 Bl[128 * 32];
  __shared__ __align__(16) u16 Cst[4][32 * 88];   // epilogue transpose (MODE 0)
  int m0 = blockIdx.x * 128, n0 = blockIdx.y * 128;
  int tid = threadIdx.x;
  int w = tid >> 6, l = tid & 63, lr = l >> 4, lc = l & 15;
  int wr = w >> 1, wc = w & 1;
  f32x4 acc[4][4] = {};
  int nkt = Kdim >> 5;
  for (int kt = 0; kt < nkt; ++kt) {
    __syncthreads();
#pragma unroll
    for (int i = 0; i < 2; ++i) {
      int idx = i * 256 + tid;              // 512 chunks of 16B per matrix
      int r = idx >> 2, c8 = (idx & 3) * 8;
      gl_lds16(A + (size_t)(m0 + r) * Kdim + kt * 32 + c8, &Al[idx * 8]);
      gl_lds16(Bt + (size_t)(n0 + r) * Kdim + kt * 32 + c8, &Bl[idx * 8]);
    }
    __syncthreads();
    short8 af[4];
#pragma unroll
    for (int mi = 0; mi < 4; ++mi)
      af[mi] = *(const short8*)&Al[(wr * 64 + mi * 16 + lc) * 32 + lr * 8];
#pragma unroll
    for (int ni = 0; ni < 4; ++ni) {
      short8 bf = *(const short8*)&Bl[(wc * 64 + ni * 16 + lc) * 32 + lr * 8];
#pragma unroll
      for (int mi = 0; mi < 4; ++mi)
        acc[mi][ni] = mfma16(af[mi], bf, acc[mi][ni]);
    }
  }

  if (MODE == 0) {
    if (n0 < 1536) {
      // transposed store through per-wave LDS (coalesced 16B global stores)
      u16* Cb = &Cst[w][0];
#pragma unroll
      for (int mi2 = 0; mi2 < 2; ++mi2) {
#pragma unroll
        for (int mh = 0; mh < 2; ++mh) {
          int mi = mi2 * 2 + mh;
#pragma unroll
          for (int ni = 0; ni < 4; ++ni) {
            float bv = bias[n0 + wc * 64 + ni * 16 + lc];
#pragma unroll
            for (int r = 0; r < 4; ++r)
              Cb[(mh * 16 + lr * 4 + r) * 88 + ni * 16 + lc] =
                  f2b(acc[mi][ni][r] + bv);
          }
        }
#pragma unroll
        for (int i = 0; i < 4; ++i) {
          int idx = i * 64 + l;
          int row = idx >> 3, c8 = idx & 7;
          short8 vv = *(const short8*)&Cb[row * 88 + c8 * 8];
          int grow = m0 + wr * 64 + mi2 * 32 + row;
          int gcol = n0 + wc * 64 + c8 * 8;
          *(short8*)(obf + (size_t)grow * Nn + gcol) = vv;
        }
      }
    } else {
      // V section: write directly in vT layout [(b*8+h)*96+d][1024]
#pragma unroll
      for (int mi = 0; mi < 4; ++mi) {
#pragma unroll
        for (int ni = 0; ni < 4; ++ni) {
          int col = n0 + wc * 64 + ni * 16 + lc;
          float bv = bias[col];
          int dall = col - 1536;                       // = h*96 + d
          int row0 = m0 + wr * 64 + mi * 16 + lr * 4;  // rows 4-aligned, same b
          short4v o4;
#pragma unroll
          for (int r = 0; r < 4; ++r) o4[r] = (short)f2b(acc[mi][ni][r] + bv);
          *(short4v*)(vtb + ((size_t)(row0 >> 10) * 768 + dall) * 1024 +
                      (row0 & 1023)) = o4;
        }
      }
    }
  } else {
#pragma unroll
    for (int mi = 0; mi < 4; ++mi) {
#pragma unroll
      for (int ni = 0; ni < 4; ++ni) {
        int col = n0 + wc * 64 + ni * 16 + lc;
        float bv = bias[col];
        int row0 = m0 + wr * 64 + mi * 16 + lr * 4;
#pragma unroll
        for (int r = 0; r < 4; ++r)
          of32[(size_t)(row0 + r) * Nn + col] = acc[mi][ni][r] + bv;
      }
    }
  }
}

// ---------- kernel 4: flash attention (r8) ----------
// Round-6 structure (best known: K gl_lds double-buffer, one barrier/tile,
// swapped QK^T, in-reg softmax) with the q-slice HALVED: block = 64 q rows
// (grid 1024 = 16 qt x 8 h x 8 b, b fastest for XCD L2 locality), 4 waves x
// 16 q rows. Halves per-wave serial chain + register state (fits the
// (256,3) 84+84 budget that 32-row waves kept spilling out of); LDS ~34 KB
// -> 3 blocks/CU = 12 waves/CU for cross-block stall filling.
__global__ __launch_bounds__(256, 3) void k_attn(const u16* __restrict__ qkvp,
                                                 const u16* __restrict__ vt,
                                                 u16* __restrict__ ctx) {
  __shared__ __align__(16) u16 smem[16896];   // Kb[2][64*96]=12288 | Pw[4][16*72]=4608
  int blk = blockIdx.x;
  int b = blk & 7, h = (blk >> 3) & 7, qt = blk >> 6;   // qt in [0,16)
  int tid = threadIdx.x, w = tid >> 6, l = tid & 63;
  int lr = l >> 4, lc = l & 15;
  int q0 = qt * 64 + w * 16;
  const u16* qptr = qkvp + (size_t)b * 1024 * 2304 + h * 96;
  const u16* kptr = qptr + 768;
  const u16* vln  = vt + (size_t)(b * 768 + h * 96) * 1024 +
                    (size_t)lc * 1024 + lr * 8;   // per-lane V base
  u16* Pw = smem + 12288 + w * 1152;          // [16][72]  (P stored [q][k])

  // K staging offsets (64 rows x 12 chunks of 8 u16 = 768 = 3 x 256)
  int soff[3], doff[3];
#pragma unroll
  for (int i = 0; i < 3; ++i) {
    int idx = i * 256 + tid;
    soff[i] = (idx / 12) * 2304 + (idx % 12) * 8;
    doff[i] = idx * 8;
  }

  // Q-frags (B-operand of swapped QK^T): Q[q0+lc][32kf+8lr+j]
  short8 qf[3];
#pragma unroll
  for (int kf = 0; kf < 3; ++kf)
    qf[kf] = *(const short8*)(qptr + (size_t)(q0 + lc) * 2304 + kf * 32 + lr * 8);

  float mrow = -INFINITY, lrow = 0.f;
  f32x4 oacc[6] = {};    // O^T[d=16nf+4lr+r][q=lc]

  // prologue: stage K tile 0
#pragma unroll
  for (int i = 0; i < 3; ++i) gl_lds16(kptr + soff[i], smem + doff[i]);
  __syncthreads();

  for (int kt = 0; kt < 16; ++kt) {
    const u16* Kc = smem + (kt & 1) * 6144;
    const u16* vkt = vln + kt * 64;

    // V frags, kchunk 0 — issued BEFORE staging so their vmcnt wait
    // (at PV chunk0) retires without draining the staging queue.
    short8 va[6];
#pragma unroll
    for (int nf = 0; nf < 6; ++nf)
      va[nf] = *(const short8*)(vkt + (size_t)nf * 16384);

    if (kt < 15) {                          // async-stage next K tile
      const u16* kg = kptr + (size_t)(kt + 1) * 64 * 2304;
      u16* db = smem + ((kt + 1) & 1) * 6144;
#pragma unroll
      for (int i = 0; i < 3; ++i) gl_lds16(kg + soff[i], db + doff[i]);
    }

    // S^T = K Q^T : sacc[kfr] holds S^T[k=16kfr+4lr+r][q=lc]
    f32x4 sacc[4] = {};
    __builtin_amdgcn_s_setprio(1);
#pragma unroll
    for (int kfr = 0; kfr < 4; ++kfr) {
#pragma unroll
      for (int kf = 0; kf < 3; ++kf) {
        short8 kb = *(const short8*)&Kc[(kfr * 16 + lc) * 96 + kf * 32 + lr * 8];
        sacc[kfr] = mfma16(kb, qf[kf], sacc[kfr]);
      }
    }
    __builtin_amdgcn_s_setprio(0);

    // online softmax (exp2 domain, deferred max THR=8), mostly in-lane
    float mx = sacc[0][0];
#pragma unroll
    for (int kfr = 0; kfr < 4; ++kfr)
#pragma unroll
      for (int r = 0; r < 4; ++r)
        if (kfr | r) mx = fmaxf(mx, sacc[kfr][r]);
    mx = fmaxf(mx, __shfl_xor(mx, 16));
    mx = fmaxf(mx, __shfl_xor(mx, 32));
    if (__any(mx > mrow + 8.f)) {     // wave-uniform, rare after tile 0
      float nm = fmaxf(mrow, mx);
      float sc = exp2f(mrow - nm);    // 0 on first tile
      mrow = nm;
      lrow *= sc;
#pragma unroll
      for (int nf = 0; nf < 6; ++nf)
#pragma unroll
        for (int r = 0; r < 4; ++r) oacc[nf][r] *= sc;
    }
    float m = mrow, rs = 0.f;
#pragma unroll
    for (int kfr = 0; kfr < 4; ++kfr) {
      float p0 = exp2f(sacc[kfr][0] - m);
      float p1 = exp2f(sacc[kfr][1] - m);
      float p2 = exp2f(sacc[kfr][2] - m);
      float p3 = exp2f(sacc[kfr][3] - m);
      rs += (p0 + p1) + (p2 + p3);
      uint2v pk;
      pk[0] = cvt_pk_bf16(p0, p1);
      pk[1] = cvt_pk_bf16(p2, p3);
      *(uint2v*)&Pw[lc * 72 + kfr * 16 + lr * 4] = pk;
    }
    rs += __shfl_xor(rs, 16);
    rs += __shfl_xor(rs, 32);
    lrow += rs;
    asm volatile("s_waitcnt lgkmcnt(0)" ::: "memory");   // P visible (own wave)

    // P frags chunk0 + V frags chunk1 (chunk1 loads hide under PV chunk0)
    short8 pb = *(const short8*)&Pw[lc * 72 + lr * 8];
    short8 vc[6];
#pragma unroll
    for (int nf = 0; nf < 6; ++nf)
      vc[nf] = *(const short8*)(vkt + (size_t)nf * 16384 + 32);

    // O^T += V^T P^T, kchunk 0
    __builtin_amdgcn_s_setprio(1);
#pragma unroll
    for (int nf = 0; nf < 6; ++nf)
      oacc[nf] = mfma16(va[nf], pb, oacc[nf]);
    __builtin_amdgcn_s_setprio(0);

    // kchunk 1
    pb = *(const short8*)&Pw[lc * 72 + 32 + lr * 8];
    __builtin_amdgcn_s_setprio(1);
#pragma unroll
    for (int nf = 0; nf < 6; ++nf)
      oacc[nf] = mfma16(vc[nf], pb, oacc[nf]);
    __builtin_amdgcn_s_setprio(0);
    __syncthreads();   // next K tile staged (vmcnt drained); Kc reads done
  }

  // epilogue: O^T -> O via per-wave LDS transpose, coalesced 16B stores
  u16* Cw = smem + w * 3328;                // [16][104] (reuse K buffers)
  float inv = 1.0f / lrow;
#pragma unroll
  for (int nf = 0; nf < 6; ++nf) {
    uint2v pk;
    pk[0] = cvt_pk_bf16(oacc[nf][0] * inv, oacc[nf][1] * inv);
    pk[1] = cvt_pk_bf16(oacc[nf][2] * inv, oacc[nf][3] * inv);
    *(uint2v*)&Cw[lc * 104 + nf * 16 + lr * 4] = pk;
  }
  asm volatile("s_waitcnt lgkmcnt(0)" ::: "memory");
  int crow0 = b * 1024 + qt * 64 + w * 16;
#pragma unroll
  for (int i = 0; i < 3; ++i) {
    int idx = i * 64 + l;                   // 16 rows x 12 chunks
    int row = idx / 12, c8 = idx % 12;
    short8 vv = *(const short8*)&Cw[row * 104 + c8 * 8];
    *(short8*)(ctx + (size_t)(crow0 + row) * 768 + h * 96 + c8 * 8) = vv;
  }
}

// ---------- launch ----------
extern "C" void kernel_launch(void* const* d_in, const int* in_sizes, int n_in,
                              void* d_out, int out_size, void* d_ws, size_t ws_size,
                              hipStream_t stream) {
  const float* x     = (const float*)d_in[0];
  const float* Wqkv  = (const float*)d_in[1];
  const float* bqkv  = (const float*)d_in[2];
  const float* Wproj = (const float*)d_in[3];
  const float* bproj = (const float*)d_in[4];
  float* out = (float*)d_out;

  char* ws = (char*)d_ws;
  u16*   xb     = (u16*)(ws);                    // 12,582,912 B (reused as ctx)
  u16*   wqkvT  = (u16*)(ws + 12582912);         //  3,538,944 B
  u16*   wprojT = (u16*)(ws + 16121856);         //  1,179,648 B
  float* bqkvp  = (float*)(ws + 17301504);       //      9,216 B
  u16*   qkvp   = (u16*)(ws + 17310720);         // 37,748,736 B (q,k cols only)
  u16*   vtb    = (u16*)(ws + 55059456);         // 12,582,912 B
  u16*   ctx    = xb;                            // xb dead after QKV GEMM

  k_cvt_x<<<6144, 256, 0, stream>>>(x, xb);
  k_tcvt<1><<<dim3(K3 / 32, Emb / 32), 256, 0, stream>>>(Wqkv, wqkvT, Emb, K3);
  k_tcvt<0><<<dim3(Emb / 32, Emb / 32), 256, 0, stream>>>(Wproj, wprojT, Emb, Emb);
  k_permbias<<<9, 256, 0, stream>>>(bqkv, bqkvp);
  k_gemm_bt<0><<<dim3(Mrows / 128, K3 / 128), 256, 0, stream>>>(
      xb, wqkvT, bqkvp, qkvp, vtb, nullptr, K3, Emb);
  k_attn<<<1024, 256, 0, stream>>>(qkvp, vtb, ctx);
  k_gemm_bt<1><<<dim3(Mrows / 128, Emb / 128), 256, 0, stream>>>(
      ctx, wprojT, bproj, nullptr, nullptr, out, Emb, Emb);
}

// Round 9
// 133.324 us; speedup vs baseline: 1.4072x; 1.3757x over previous
//
#include <hip/hip_runtime.h>

typedef unsigned short u16;
typedef __attribute__((ext_vector_type(8))) short short8;   // 8 bf16 (guide §3 frag_ab)
typedef __attribute__((ext_vector_type(4))) short short4v;
typedef __attribute__((ext_vector_type(4))) float f32x4;    // frag_cd
typedef __attribute__((ext_vector_type(2))) unsigned int uint2v;

#define DEV static __device__ __forceinline__

static_assert(sizeof(short8) == 16, "short8 must be 16B");

// ---------- helpers ----------
DEV u16 f2b(float f) {                       // fp32 -> bf16, round-to-nearest-even
  union { float f; unsigned u; } a; a.f = f;
  unsigned u = a.u;
  unsigned r = (u + 0x7FFFu + ((u >> 16) & 1u)) >> 16;
  return (u16)r;
}

DEV unsigned cvt_pk_bf16(float lo, float hi) {   // {bf16(lo), bf16(hi)} packed
  unsigned r;
  asm("v_cvt_pk_bf16_f32 %0, %1, %2" : "=v"(r) : "v"(lo), "v"(hi));
  return r;
}

// MFMA via builtin: compiler manages hazards + allocates accumulators on the
// AGPR side of the gfx950 unified file (r5->r6 lesson: +18 us from this alone).
DEV f32x4 mfma16(short8 a, short8 b, f32x4 c) {
  return __builtin_amdgcn_mfma_f32_16x16x32_bf16(a, b, c, 0, 0, 0);
}

// async global->LDS, 16B per lane; LDS dest must be wave-uniform base + lane*16
DEV void gl_lds16(const u16* g, u16* l) {
  __builtin_amdgcn_global_load_lds(
      (const __attribute__((address_space(1))) void*)g,
      (__attribute__((address_space(3))) void*)l, 16, 0, 0);
}

// ---------- problem dims ----------
constexpr int Bz = 8, Nseq = 1024, Emb = 768, Hh = 8, Dh = 96;
constexpr int Mrows = Bz * Nseq;    // 8192
constexpr int K3 = 3 * Emb;         // 2304
// 768^-0.5 * log2(e): softmax done in exp2 domain (saves a mul per S element)
constexpr float QSCALE = 0.05205982021128899f;

// ---------- kernel 1: x fp32 -> bf16 ----------
__global__ __launch_bounds__(256) void k_cvt_x(const float* __restrict__ src,
                                               u16* __restrict__ dst) {
  int i = (blockIdx.x * 256 + threadIdx.x) * 4;
  float4 v = *(const float4*)(src + i);
  short4v o;
  o[0] = (short)f2b(v.x); o[1] = (short)f2b(v.y);
  o[2] = (short)f2b(v.z); o[3] = (short)f2b(v.w);
  *(short4v*)(dst + i) = o;
}

// ---------- kernel 2: transpose + cvt (+optional qkv column permutation) ----------
template <int PERM>
__global__ __launch_bounds__(256) void k_tcvt(const float* __restrict__ src,
                                              u16* __restrict__ dst, int R, int C) {
  __shared__ float t[32][33];
  int bx = blockIdx.x * 32;   // col tile in src
  int by = blockIdx.y * 32;   // row tile in src
  int c = threadIdx.x & 31, r8 = threadIdx.x >> 5;
#pragma unroll
  for (int p = 0; p < 4; ++p) {
    int r = r8 + p * 8;
    t[r][c] = src[(size_t)(by + r) * C + bx + c];
  }
  __syncthreads();
#pragma unroll
  for (int p = 0; p < 4; ++p) {
    int r = r8 + p * 8;
    int co = bx + r;           // dst row before permutation = src col
    int row = co;
    float mul = 1.f;
    if (PERM) {
      int h = co / 288, rem = co - h * 288;
      int d = rem / 3, s = rem - d * 3;
      row = s * 768 + h * 96 + d;
      if (s == 0) mul = QSCALE;
    }
    dst[(size_t)row * R + by + c] = f2b(t[c][r] * mul);
  }
}

// ---------- kernel 2b: permuted (and q-scaled) qkv bias, fp32 ----------
__global__ __launch_bounds__(256) void k_permbias(const float* __restrict__ b,
                                                  float* __restrict__ bp) {
  int co = blockIdx.x * 256 + threadIdx.x;
  if (co < 2304) {
    int h = co / 288, rem = co - h * 288, d = rem / 3, s = rem - d * 3;
    bp[s * 768 + h * 96 + d] = b[co] * (s == 0 ? QSCALE : 1.f);
  }
}

// ---------- kernel 3: GEMM  C[M][Nn] = A[M][K] * Bt[Nn][K]^T + bias ----------
// r9: T3/T4 pipeline — TRIPLE-buffered LDS staged 2 K-steps ahead; ONE barrier
// per step with counted s_waitcnt vmcnt(4) (never 0 mid-loop) so staging
// latency hides under MFMA of the 2 preceding steps. Cst aliased over the
// staging buffers (barrier-guarded) to stay under the 64KB static LDS limit.
// MODE 0: QKV gemm. cols<1536 -> LDS-transposed bf16 store to obf[.][2304];
//         cols>=1536 -> direct store into vT[B*H*96][1024].
// MODE 1: proj gemm, f32 direct store.
template <int MODE>
__global__ __launch_bounds__(256, 2) void k_gemm_bt(
    const u16* __restrict__ A, const u16* __restrict__ Bt,
    const float* __restrict__ bias,
    u16* __restrict__ obf, u16* __restrict__ vtb, float* __restrict__ of32,
    int Nn, int Kdim) {
  __shared__ __align__(16) u16 smem[24576];   // 49152 B: A0 A1 A2 B0 B1 B2
  int m0 = blockIdx.x * 128, n0 = blockIdx.y * 128;
  int tid = threadIdx.x;
  int w = tid >> 6, l = tid & 63, lr = l >> 4, lc = l & 15;
  int wr = w >> 1, wc = w & 1;
  f32x4 acc[4][4] = {};
  int nkt = Kdim >> 5;    // 24

  auto stage = [&](u16* bA, u16* bB, int t) {
#pragma unroll
    for (int i = 0; i < 2; ++i) {
      int idx = i * 256 + tid;              // 512 chunks of 16B per matrix
      int rr = idx >> 2, cc = (idx & 3) * 8;
      gl_lds16(A + (size_t)(m0 + rr) * Kdim + t * 32 + cc, bA + idx * 8);
      gl_lds16(Bt + (size_t)(n0 + rr) * Kdim + t * 32 + cc, bB + idx * 8);
    }
  };

  u16 *a0 = smem, *a1 = smem + 4096, *a2 = smem + 8192;
  u16 *b0 = smem + 12288, *b1 = smem + 16384, *b2 = smem + 20480;
  stage(a0, b0, 0);
  stage(a1, b1, 1);

  for (int kt = 0; kt < nkt; ++kt) {
    // tile kt staged 2 iterations ago -> counted wait, latency hidden.
    if (kt < nkt - 1)
      asm volatile("s_waitcnt vmcnt(4) lgkmcnt(0)\n\ts_barrier" ::: "memory");
    else
      asm volatile("s_waitcnt vmcnt(0) lgkmcnt(0)\n\ts_barrier" ::: "memory");
    if (kt + 2 < nkt) stage(a2, b2, kt + 2);   // overwrites tile kt-1's buffer
    short8 af[4];
#pragma unroll
    for (int mi = 0; mi < 4; ++mi)
      af[mi] = *(const short8*)&a0[(wr * 64 + mi * 16 + lc) * 32 + lr * 8];
#pragma unroll
    for (int ni = 0; ni < 4; ++ni) {
      short8 bf = *(const short8*)&b0[(wc * 64 + ni * 16 + lc) * 32 + lr * 8];
#pragma unroll
      for (int mi = 0; mi < 4; ++mi)
        acc[mi][ni] = mfma16(af[mi], bf, acc[mi][ni]);
    }
    u16* t;
    t = a0; a0 = a1; a1 = a2; a2 = t;
    t = b0; b0 = b1; b1 = b2; b2 = t;
  }
  __syncthreads();   // staging buffers dead; Cst aliases them below

  if (MODE == 0) {
    if (n0 < 1536) {
      // transposed store through per-wave LDS (coalesced 16B global stores)
      u16* Cb = smem + w * 2816;              // [32][88] per wave
#pragma unroll
      for (int mi2 = 0; mi2 < 2; ++mi2) {
#pragma unroll
        for (int mh = 0; mh < 2; ++mh) {
          int mi = mi2 * 2 + mh;
#pragma unroll
          for (int ni = 0; ni < 4; ++ni) {
            float bv = bias[n0 + wc * 64 + ni * 16 + lc];
#pragma unroll
            for (int r = 0; r < 4; ++r)
              Cb[(mh * 16 + lr * 4 + r) * 88 + ni * 16 + lc] =
                  f2b(acc[mi][ni][r] + bv);
          }
        }
#pragma unroll
        for (int i = 0; i < 4; ++i) {
          int idx = i * 64 + l;
          int row = idx >> 3, c8 = idx & 7;
          short8 vv = *(const short8*)&Cb[row * 88 + c8 * 8];
          int grow = m0 + wr * 64 + mi2 * 32 + row;
          int gcol = n0 + wc * 64 + c8 * 8;
          *(short8*)(obf + (size_t)grow * Nn + gcol) = vv;
        }
      }
    } else {
      // V section: write directly in vT layout [(b*8+h)*96+d][1024]
#pragma unroll
      for (int mi = 0; mi < 4; ++mi) {
#pragma unroll
        for (int ni = 0; ni < 4; ++ni) {
          int col = n0 + wc * 64 + ni * 16 + lc;
          float bv = bias[col];
          int dall = col - 1536;                       // = h*96 + d
          int row0 = m0 + wr * 64 + mi * 16 + lr * 4;  // rows 4-aligned, same b
          short4v o4;
#pragma unroll
          for (int r = 0; r < 4; ++r) o4[r] = (short)f2b(acc[mi][ni][r] + bv);
          *(short4v*)(vtb + ((size_t)(row0 >> 10) * 768 + dall) * 1024 +
                      (row0 & 1023)) = o4;
        }
      }
    }
  } else {
#pragma unroll
    for (int mi = 0; mi < 4; ++mi) {
#pragma unroll
      for (int ni = 0; ni < 4; ++ni) {
        int col = n0 + wc * 64 + ni * 16 + lc;
        float bv = bias[col];
        int row0 = m0 + wr * 64 + mi * 16 + lr * 4;
#pragma unroll
        for (int r = 0; r < 4; ++r)
          of32[(size_t)(row0 + r) * Nn + col] = acc[mi][ni][r] + bv;
      }
    }
  }
}

// ---------- kernel 4: flash attention (r9 = r6 geometry + vmem reorder) ----------
// block = (qt,h,b), b fastest (XCD L2 locality). 4 waves x 32 q rows.
// S^T = K·Q^T (lane holds a q-row's scores along k); PV as O^T = V^T·P^T.
// K double-buffered LDS via gl_lds. r9 FIX: per-tile vmem order is
// va, vc, THEN staging — so PV0 waits vmcnt(9), PV1 waits vmcnt(3), and the
// tile-end barrier's vmcnt(0) hits staging issued a full tile earlier.
// (r6 issued vc AFTER staging -> PV1's wait drained the staging queue every
// tile.) (256,2): grid = 2 blocks/CU, don't squeeze regs for unreachable occ.
__global__ __launch_bounds__(256, 2) void k_attn(const u16* __restrict__ qkvp,
                                                 const u16* __restrict__ vt,
                                                 u16* __restrict__ ctx) {
  __shared__ __align__(16) u16 smem[21504];   // Kb[2][64*96] | Pw[4][32*72]
  int blk = blockIdx.x;
  int b = blk & 7, h = (blk >> 3) & 7, qt = blk >> 6;
  int tid = threadIdx.x, w = tid >> 6, l = tid & 63;
  int lr = l >> 4, lc = l & 15;
  int q0 = qt * 128 + w * 32;
  const u16* qptr = qkvp + (size_t)b * 1024 * 2304 + h * 96;
  const u16* kptr = qptr + 768;
  const u16* vtp  = vt + (size_t)(b * 768 + h * 96) * 1024 +
                    (size_t)lc * 1024 + lr * 8;   // per-lane V base
  u16* Pw = smem + 12288 + w * 2304;          // [32][72]  (P stored [q][k])

  // K staging offsets (64 rows x 12 chunks of 8 u16 = 768 = 3 x 256)
  int soff[3], doff[3];
#pragma unroll
  for (int i = 0; i < 3; ++i) {
    int idx = i * 256 + tid;
    soff[i] = (idx / 12) * 2304 + (idx % 12) * 8;
    doff[i] = idx * 8;
  }

  // Q-frags (B-operand of swapped QK^T): Q[q0+16qi+lc][32kf+8lr+j]
  short8 qf[2][3];
#pragma unroll
  for (int qi = 0; qi < 2; ++qi)
#pragma unroll
    for (int kf = 0; kf < 3; ++kf)
      qf[qi][kf] = *(const short8*)(qptr + (size_t)(q0 + qi * 16 + lc) * 2304 +
                                    kf * 32 + lr * 8);

  float mrow[2] = {-INFINITY, -INFINITY}, lrow[2] = {0.f, 0.f};
  f32x4 oacc[2][6] = {};    // O^T[d=16nf+4lr+r][q=16qi+lc]

  // prologue: stage K tile 0
#pragma unroll
  for (int i = 0; i < 3; ++i) gl_lds16(kptr + soff[i], smem + doff[i]);
  __syncthreads();

  for (int kt = 0; kt < 16; ++kt) {
    const u16* Kc = smem + (kt & 1) * 6144;
    const u16* vkt = vtp + kt * 64;

    // ALL of this tile's V frags issue first (before staging) so their
    // vmcnt waits (9 / 3) never drain the staging queue.
    short8 va[6], vc[6];
#pragma unroll
    for (int nf = 0; nf < 6; ++nf) {
      va[nf] = *(const short8*)(vkt + (size_t)nf * 16384);
      vc[nf] = *(const short8*)(vkt + (size_t)nf * 16384 + 32);
    }
    asm volatile("" ::: "memory");         // pin staging after the V loads

    if (kt < 15) {                          // async-stage next K tile
      const u16* kg = kptr + (size_t)(kt + 1) * 64 * 2304;
      u16* db = smem + ((kt + 1) & 1) * 6144;
#pragma unroll
      for (int i = 0; i < 3; ++i) gl_lds16(kg + soff[i], db + doff[i]);
    }

    // S^T = K Q^T : sacc[qi][kfr] holds S^T[k=16kfr+4lr+r][q=16qi+lc]
    f32x4 sacc[2][4] = {};
    __builtin_amdgcn_s_setprio(1);
#pragma unroll
    for (int kfr = 0; kfr < 4; ++kfr) {
#pragma unroll
      for (int kf = 0; kf < 3; ++kf) {
        short8 kb = *(const short8*)&Kc[(kfr * 16 + lc) * 96 + kf * 32 + lr * 8];
        sacc[0][kfr] = mfma16(kb, qf[0][kf], sacc[0][kfr]);
        sacc[1][kfr] = mfma16(kb, qf[1][kf], sacc[1][kfr]);
      }
    }
    __builtin_amdgcn_s_setprio(0);

    // online softmax (exp2 domain, deferred max THR=8), mostly in-lane
#pragma unroll
    for (int qi = 0; qi < 2; ++qi) {
      float mx = sacc[qi][0][0];
#pragma unroll
      for (int kfr = 0; kfr < 4; ++kfr)
#pragma unroll
        for (int r = 0; r < 4; ++r)
          if (kfr | r) mx = fmaxf(mx, sacc[qi][kfr][r]);
      mx = fmaxf(mx, __shfl_xor(mx, 16));
      mx = fmaxf(mx, __shfl_xor(mx, 32));
      if (__any(mx > mrow[qi] + 8.f)) {     // wave-uniform, rare after tile 0
        float nm = fmaxf(mrow[qi], mx);
        float sc = exp2f(mrow[qi] - nm);    // 0 on first tile
        mrow[qi] = nm;
        lrow[qi] *= sc;
#pragma unroll
        for (int nf = 0; nf < 6; ++nf)
#pragma unroll
          for (int r = 0; r < 4; ++r) oacc[qi][nf][r] *= sc;
      }
      float m = mrow[qi], rs = 0.f;
#pragma unroll
      for (int kfr = 0; kfr < 4; ++kfr) {
        float p0 = exp2f(sacc[qi][kfr][0] - m);
        float p1 = exp2f(sacc[qi][kfr][1] - m);
        float p2 = exp2f(sacc[qi][kfr][2] - m);
        float p3 = exp2f(sacc[qi][kfr][3] - m);
        rs += (p0 + p1) + (p2 + p3);
        uint2v pk;
        pk[0] = cvt_pk_bf16(p0, p1);
        pk[1] = cvt_pk_bf16(p2, p3);
        *(uint2v*)&Pw[(qi * 16 + lc) * 72 + kfr * 16 + lr * 4] = pk;
      }
      rs += __shfl_xor(rs, 16);
      rs += __shfl_xor(rs, 32);
      lrow[qi] += rs;
    }
    asm volatile("s_waitcnt lgkmcnt(0)" ::: "memory");   // P visible (own wave)

    // O^T += V^T P^T, kchunk 0  (va wait: vmcnt(9) -- staging stays in flight)
    short8 pb0 = *(const short8*)&Pw[lc * 72 + lr * 8];
    short8 pb1 = *(const short8*)&Pw[(16 + lc) * 72 + lr * 8];
    __builtin_amdgcn_s_setprio(1);
#pragma unroll
    for (int nf = 0; nf < 6; ++nf) {
      oacc[0][nf] = mfma16(va[nf], pb0, oacc[0][nf]);
      oacc[1][nf] = mfma16(va[nf], pb1, oacc[1][nf]);
    }
    __builtin_amdgcn_s_setprio(0);

    // kchunk 1  (vc wait: vmcnt(3))
    pb0 = *(const short8*)&Pw[lc * 72 + 32 + lr * 8];
    pb1 = *(const short8*)&Pw[(16 + lc) * 72 + 32 + lr * 8];
    __builtin_amdgcn_s_setprio(1);
#pragma unroll
    for (int nf = 0; nf < 6; ++nf) {
      oacc[0][nf] = mfma16(vc[nf], pb0, oacc[0][nf]);
      oacc[1][nf] = mfma16(vc[nf], pb1, oacc[1][nf]);
    }
    __builtin_amdgcn_s_setprio(0);
    __syncthreads();   // staging (issued at tile top) long since landed
  }

  // epilogue: O^T -> O via per-wave LDS transpose, coalesced 16B stores
  u16* Cw = smem + w * 3328;                // [32][104]
  float inv[2] = {1.0f / lrow[0], 1.0f / lrow[1]};
#pragma unroll
  for (int qi = 0; qi < 2; ++qi) {
#pragma unroll
    for (int nf = 0; nf < 6; ++nf) {
      uint2v pk;
      pk[0] = cvt_pk_bf16(oacc[qi][nf][0] * inv[qi], oacc[qi][nf][1] * inv[qi]);
      pk[1] = cvt_pk_bf16(oacc[qi][nf][2] * inv[qi], oacc[qi][nf][3] * inv[qi]);
      *(uint2v*)&Cw[(qi * 16 + lc) * 104 + nf * 16 + lr * 4] = pk;
    }
  }
  asm volatile("s_waitcnt lgkmcnt(0)" ::: "memory");
  int crow0 = b * 1024 + qt * 128 + w * 32;
#pragma unroll
  for (int i = 0; i < 6; ++i) {
    int idx = i * 64 + l;                   // 32 rows x 12 chunks
    int row = idx / 12, c8 = idx % 12;
    short8 vv = *(const short8*)&Cw[row * 104 + c8 * 8];
    *(short8*)(ctx + (size_t)(crow0 + row) * 768 + h * 96 + c8 * 8) = vv;
  }
}

// ---------- launch ----------
extern "C" void kernel_launch(void* const* d_in, const int* in_sizes, int n_in,
                              void* d_out, int out_size, void* d_ws, size_t ws_size,
                              hipStream_t stream) {
  const float* x     = (const float*)d_in[0];
  const float* Wqkv  = (const float*)d_in[1];
  const float* bqkv  = (const float*)d_in[2];
  const float* Wproj = (const float*)d_in[3];
  const float* bproj = (const float*)d_in[4];
  float* out = (float*)d_out;

  char* ws = (char*)d_ws;
  u16*   xb     = (u16*)(ws);                    // 12,582,912 B (reused as ctx)
  u16*   wqkvT  = (u16*)(ws + 12582912);         //  3,538,944 B
  u16*   wprojT = (u16*)(ws + 16121856);         //  1,179,648 B
  float* bqkvp  = (float*)(ws + 17301504);       //      9,216 B
  u16*   qkvp   = (u16*)(ws + 17310720);         // 37,748,736 B (q,k cols only)
  u16*   vtb    = (u16*)(ws + 55059456);         // 12,582,912 B
  u16*   ctx    = xb;                            // xb dead after QKV GEMM

  k_cvt_x<<<6144, 256, 0, stream>>>(x, xb);
  k_tcvt<1><<<dim3(K3 / 32, Emb / 32), 256, 0, stream>>>(Wqkv, wqkvT, Emb, K3);
  k_tcvt<0><<<dim3(Emb / 32, Emb / 32), 256, 0, stream>>>(Wproj, wprojT, Emb, Emb);
  k_permbias<<<9, 256, 0, stream>>>(bqkv, bqkvp);
  k_gemm_bt<0><<<dim3(Mrows / 128, K3 / 128), 256, 0, stream>>>(
      xb, wqkvT, bqkvp, qkvp, vtb, nullptr, K3, Emb);
  k_attn<<<512, 256, 0, stream>>>(qkvp, vtb, ctx);
  k_gemm_bt<1><<<dim3(Mrows / 128, Emb / 128), 256, 0, stream>>>(
      ctx, wprojT, bproj, nullptr, nullptr, out, Emb, Emb);
}

// Round 10
// 133.226 us; speedup vs baseline: 1.4083x; 1.0007x over previous
//
#include <hip/hip_runtime.h>

typedef unsigned short u16;
typedef __attribute__((ext_vector_type(8))) short short8;   // 8 bf16 (guide §3 frag_ab)
typedef __attribute__((ext_vector_type(4))) short short4v;
typedef __attribute__((ext_vector_type(4))) float f32x4;    // frag_cd
typedef __attribute__((ext_vector_type(2))) unsigned int uint2v;

#define DEV static __device__ __forceinline__

static_assert(sizeof(short8) == 16, "short8 must be 16B");

// ---------- helpers ----------
DEV u16 f2b(float f) {                       // fp32 -> bf16, round-to-nearest-even
  union { float f; unsigned u; } a; a.f = f;
  unsigned u = a.u;
  unsigned r = (u + 0x7FFFu + ((u >> 16) & 1u)) >> 16;
  return (u16)r;
}

DEV unsigned cvt_pk_bf16(float lo, float hi) {   // {bf16(lo), bf16(hi)} packed
  unsigned r;
  asm("v_cvt_pk_bf16_f32 %0, %1, %2" : "=v"(r) : "v"(lo), "v"(hi));
  return r;
}

// MFMA via builtin: compiler manages hazards + allocates accumulators on the
// AGPR side of the gfx950 unified file (r5->r6 lesson: +18 us from this alone).
DEV f32x4 mfma16(short8 a, short8 b, f32x4 c) {
  return __builtin_amdgcn_mfma_f32_16x16x32_bf16(a, b, c, 0, 0, 0);
}

// async global->LDS, 16B per lane; LDS dest must be wave-uniform base + lane*16
DEV void gl_lds16(const u16* g, u16* l) {
  __builtin_amdgcn_global_load_lds(
      (const __attribute__((address_space(1))) void*)g,
      (__attribute__((address_space(3))) void*)l, 16, 0, 0);
}

// ---------- problem dims ----------
constexpr int Bz = 8, Nseq = 1024, Emb = 768, Hh = 8, Dh = 96;
constexpr int Mrows = Bz * Nseq;    // 8192
constexpr int K3 = 3 * Emb;         // 2304
// 768^-0.5 * log2(e): softmax done in exp2 domain (saves a mul per S element)
constexpr float QSCALE = 0.05205982021128899f;

// ---------- kernel 1: x fp32 -> bf16 ----------
__global__ __launch_bounds__(256) void k_cvt_x(const float* __restrict__ src,
                                               u16* __restrict__ dst) {
  int i = (blockIdx.x * 256 + threadIdx.x) * 4;
  float4 v = *(const float4*)(src + i);
  short4v o;
  o[0] = (short)f2b(v.x); o[1] = (short)f2b(v.y);
  o[2] = (short)f2b(v.z); o[3] = (short)f2b(v.w);
  *(short4v*)(dst + i) = o;
}

// ---------- kernel 2: transpose + cvt (+optional qkv column permutation) ----------
template <int PERM>
__global__ __launch_bounds__(256) void k_tcvt(const float* __restrict__ src,
                                              u16* __restrict__ dst, int R, int C) {
  __shared__ float t[32][33];
  int bx = blockIdx.x * 32;   // col tile in src
  int by = blockIdx.y * 32;   // row tile in src
  int c = threadIdx.x & 31, r8 = threadIdx.x >> 5;
#pragma unroll
  for (int p = 0; p < 4; ++p) {
    int r = r8 + p * 8;
    t[r][c] = src[(size_t)(by + r) * C + bx + c];
  }
  __syncthreads();
#pragma unroll
  for (int p = 0; p < 4; ++p) {
    int r = r8 + p * 8;
    int co = bx + r;           // dst row before permutation = src col
    int row = co;
    float mul = 1.f;
    if (PERM) {
      int h = co / 288, rem = co - h * 288;
      int d = rem / 3, s = rem - d * 3;
      row = s * 768 + h * 96 + d;
      if (s == 0) mul = QSCALE;
    }
    dst[(size_t)row * R + by + c] = f2b(t[c][r] * mul);
  }
}

// ---------- kernel 2b: permuted (and q-scaled) qkv bias, fp32 ----------
__global__ __launch_bounds__(256) void k_permbias(const float* __restrict__ b,
                                                  float* __restrict__ bp) {
  int co = blockIdx.x * 256 + threadIdx.x;
  if (co < 2304) {
    int h = co / 288, rem = co - h * 288, d = rem / 3, s = rem - d * 3;
    bp[s * 768 + h * 96 + d] = b[co] * (s == 0 ? QSCALE : 1.f);
  }
}

// ---------- kernel 3: GEMM  C[M][Nn] = A[M][K] * Bt[Nn][K]^T + bias ----------
// r9: T3/T4 pipeline — TRIPLE-buffered LDS staged 2 K-steps ahead; ONE barrier
// per step with counted s_waitcnt vmcnt(4) (never 0 mid-loop) so staging
// latency hides under MFMA of the 2 preceding steps. Cst aliased over the
// staging buffers (barrier-guarded) to stay under the 64KB static LDS limit.
// MODE 0: QKV gemm. cols<1536 -> LDS-transposed bf16 store to obf[.][2304];
//         cols>=1536 -> direct store into vT[B*H*96][1024].
// MODE 1: proj gemm, f32 direct store.
template <int MODE>
__global__ __launch_bounds__(256, 2) void k_gemm_bt(
    const u16* __restrict__ A, const u16* __restrict__ Bt,
    const float* __restrict__ bias,
    u16* __restrict__ obf, u16* __restrict__ vtb, float* __restrict__ of32,
    int Nn, int Kdim) {
  __shared__ __align__(16) u16 smem[24576];   // 49152 B: A0 A1 A2 B0 B1 B2
  int m0 = blockIdx.x * 128, n0 = blockIdx.y * 128;
  int tid = threadIdx.x;
  int w = tid >> 6, l = tid & 63, lr = l >> 4, lc = l & 15;
  int wr = w >> 1, wc = w & 1;
  f32x4 acc[4][4] = {};
  int nkt = Kdim >> 5;    // 24

  auto stage = [&](u16* bA, u16* bB, int t) {
#pragma unroll
    for (int i = 0; i < 2; ++i) {
      int idx = i * 256 + tid;              // 512 chunks of 16B per matrix
      int rr = idx >> 2, cc = (idx & 3) * 8;
      gl_lds16(A + (size_t)(m0 + rr) * Kdim + t * 32 + cc, bA + idx * 8);
      gl_lds16(Bt + (size_t)(n0 + rr) * Kdim + t * 32 + cc, bB + idx * 8);
    }
  };

  u16 *a0 = smem, *a1 = smem + 4096, *a2 = smem + 8192;
  u16 *b0 = smem + 12288, *b1 = smem + 16384, *b2 = smem + 20480;
  stage(a0, b0, 0);
  stage(a1, b1, 1);

  for (int kt = 0; kt < nkt; ++kt) {
    // tile kt staged 2 iterations ago -> counted wait, latency hidden.
    if (kt < nkt - 1)
      asm volatile("s_waitcnt vmcnt(4) lgkmcnt(0)\n\ts_barrier" ::: "memory");
    else
      asm volatile("s_waitcnt vmcnt(0) lgkmcnt(0)\n\ts_barrier" ::: "memory");
    if (kt + 2 < nkt) stage(a2, b2, kt + 2);   // overwrites tile kt-1's buffer
    short8 af[4];
#pragma unroll
    for (int mi = 0; mi < 4; ++mi)
      af[mi] = *(const short8*)&a0[(wr * 64 + mi * 16 + lc) * 32 + lr * 8];
#pragma unroll
    for (int ni = 0; ni < 4; ++ni) {
      short8 bf = *(const short8*)&b0[(wc * 64 + ni * 16 + lc) * 32 + lr * 8];
#pragma unroll
      for (int mi = 0; mi < 4; ++mi)
        acc[mi][ni] = mfma16(af[mi], bf, acc[mi][ni]);
    }
    u16* t;
    t = a0; a0 = a1; a1 = a2; a2 = t;
    t = b0; b0 = b1; b1 = b2; b2 = t;
  }
  __syncthreads();   // staging buffers dead; Cst aliases them below

  if (MODE == 0) {
    if (n0 < 1536) {
      // transposed store through per-wave LDS (coalesced 16B global stores)
      u16* Cb = smem + w * 2816;              // [32][88] per wave
#pragma unroll
      for (int mi2 = 0; mi2 < 2; ++mi2) {
#pragma unroll
        for (int mh = 0; mh < 2; ++mh) {
          int mi = mi2 * 2 + mh;
#pragma unroll
          for (int ni = 0; ni < 4; ++ni) {
            float bv = bias[n0 + wc * 64 + ni * 16 + lc];
#pragma unroll
            for (int r = 0; r < 4; ++r)
              Cb[(mh * 16 + lr * 4 + r) * 88 + ni * 16 + lc] =
                  f2b(acc[mi][ni][r] + bv);
          }
        }
#pragma unroll
        for (int i = 0; i < 4; ++i) {
          int idx = i * 64 + l;
          int row = idx >> 3, c8 = idx & 7;
          short8 vv = *(const short8*)&Cb[row * 88 + c8 * 8];
          int grow = m0 + wr * 64 + mi2 * 32 + row;
          int gcol = n0 + wc * 64 + c8 * 8;
          *(short8*)(obf + (size_t)grow * Nn + gcol) = vv;
        }
      }
    } else {
      // V section: write directly in vT layout [(b*8+h)*96+d][1024]
#pragma unroll
      for (int mi = 0; mi < 4; ++mi) {
#pragma unroll
        for (int ni = 0; ni < 4; ++ni) {
          int col = n0 + wc * 64 + ni * 16 + lc;
          float bv = bias[col];
          int dall = col - 1536;                       // = h*96 + d
          int row0 = m0 + wr * 64 + mi * 16 + lr * 4;  // rows 4-aligned, same b
          short4v o4;
#pragma unroll
          for (int r = 0; r < 4; ++r) o4[r] = (short)f2b(acc[mi][ni][r] + bv);
          *(short4v*)(vtb + ((size_t)(row0 >> 10) * 768 + dall) * 1024 +
                      (row0 & 1023)) = o4;
        }
      }
    }
  } else {
#pragma unroll
    for (int mi = 0; mi < 4; ++mi) {
#pragma unroll
      for (int ni = 0; ni < 4; ++ni) {
        int col = n0 + wc * 64 + ni * 16 + lc;
        float bv = bias[col];
        int row0 = m0 + wr * 64 + mi * 16 + lr * 4;
#pragma unroll
        for (int r = 0; r < 4; ++r)
          of32[(size_t)(row0 + r) * Nn + col] = acc[mi][ni][r] + bv;
      }
    }
  }
}

// ---------- kernel 4: flash attention (r9 = r6 geometry + vmem reorder) ----------
// block = (qt,h,b), b fastest (XCD L2 locality). 4 waves x 32 q rows.
// S^T = K·Q^T (lane holds a q-row's scores along k); PV as O^T = V^T·P^T.
// K double-buffered LDS via gl_lds. r9 FIX: per-tile vmem order is
// va, vc, THEN staging — so PV0 waits vmcnt(9), PV1 waits vmcnt(3), and the
// tile-end barrier's vmcnt(0) hits staging issued a full tile earlier.
// (r6 issued vc AFTER staging -> PV1's wait drained the staging queue every
// tile.) (256,2): grid = 2 blocks/CU, don't squeeze regs for unreachable occ.
__global__ __launch_bounds__(256, 2) void k_attn(const u16* __restrict__ qkvp,
                                                 const u16* __restrict__ vt,
                                                 u16* __restrict__ ctx) {
  __shared__ __align__(16) u16 smem[21504];   // Kb[2][64*96] | Pw[4][32*72]
  int blk = blockIdx.x;
  int b = blk & 7, h = (blk >> 3) & 7, qt = blk >> 6;
  int tid = threadIdx.x, w = tid >> 6, l = tid & 63;
  int lr = l >> 4, lc = l & 15;
  int q0 = qt * 128 + w * 32;
  const u16* qptr = qkvp + (size_t)b * 1024 * 2304 + h * 96;
  const u16* kptr = qptr + 768;
  const u16* vtp  = vt + (size_t)(b * 768 + h * 96) * 1024 +
                    (size_t)lc * 1024 + lr * 8;   // per-lane V base
  u16* Pw = smem + 12288 + w * 2304;          // [32][72]  (P stored [q][k])

  // K staging offsets (64 rows x 12 chunks of 8 u16 = 768 = 3 x 256)
  int soff[3], doff[3];
#pragma unroll
  for (int i = 0; i < 3; ++i) {
    int idx = i * 256 + tid;
    soff[i] = (idx / 12) * 2304 + (idx % 12) * 8;
    doff[i] = idx * 8;
  }

  // Q-frags (B-operand of swapped QK^T): Q[q0+16qi+lc][32kf+8lr+j]
  short8 qf[2][3];
#pragma unroll
  for (int qi = 0; qi < 2; ++qi)
#pragma unroll
    for (int kf = 0; kf < 3; ++kf)
      qf[qi][kf] = *(const short8*)(qptr + (size_t)(q0 + qi * 16 + lc) * 2304 +
                                    kf * 32 + lr * 8);

  float mrow[2] = {-INFINITY, -INFINITY}, lrow[2] = {0.f, 0.f};
  f32x4 oacc[2][6] = {};    // O^T[d=16nf+4lr+r][q=16qi+lc]

  // prologue: stage K tile 0
#pragma unroll
  for (int i = 0; i < 3; ++i) gl_lds16(kptr + soff[i], smem + doff[i]);
  __syncthreads();

  for (int kt = 0; kt < 16; ++kt) {
    const u16* Kc = smem + (kt & 1) * 6144;
    const u16* vkt = vtp + kt * 64;

    // ALL of this tile's V frags issue first (before staging) so their
    // vmcnt waits (9 / 3) never drain the staging queue.
    short8 va[6], vc[6];
#pragma unroll
    for (int nf = 0; nf < 6; ++nf) {
      va[nf] = *(const short8*)(vkt + (size_t)nf * 16384);
      vc[nf] = *(const short8*)(vkt + (size_t)nf * 16384 + 32);
    }
    asm volatile("" ::: "memory");         // pin staging after the V loads

    if (kt < 15) {                          // async-stage next K tile
      const u16* kg = kptr + (size_t)(kt + 1) * 64 * 2304;
      u16* db = smem + ((kt + 1) & 1) * 6144;
#pragma unroll
      for (int i = 0; i < 3; ++i) gl_lds16(kg + soff[i], db + doff[i]);
    }

    // S^T = K Q^T : sacc[qi][kfr] holds S^T[k=16kfr+4lr+r][q=16qi+lc]
    f32x4 sacc[2][4] = {};
    __builtin_amdgcn_s_setprio(1);
#pragma unroll
    for (int kfr = 0; kfr < 4; ++kfr) {
#pragma unroll
      for (int kf = 0; kf < 3; ++kf) {
        short8 kb = *(const short8*)&Kc[(kfr * 16 + lc) * 96 + kf * 32 + lr * 8];
        sacc[0][kfr] = mfma16(kb, qf[0][kf], sacc[0][kfr]);
        sacc[1][kfr] = mfma16(kb, qf[1][kf], sacc[1][kfr]);
      }
    }
    __builtin_amdgcn_s_setprio(0);

    // online softmax (exp2 domain, deferred max THR=8), mostly in-lane
#pragma unroll
    for (int qi = 0; qi < 2; ++qi) {
      float mx = sacc[qi][0][0];
#pragma unroll
      for (int kfr = 0; kfr < 4; ++kfr)
#pragma unroll
        for (int r = 0; r < 4; ++r)
          if (kfr | r) mx = fmaxf(mx, sacc[qi][kfr][r]);
      mx = fmaxf(mx, __shfl_xor(mx, 16));
      mx = fmaxf(mx, __shfl_xor(mx, 32));
      if (__any(mx > mrow[qi] + 8.f)) {     // wave-uniform, rare after tile 0
        float nm = fmaxf(mrow[qi], mx);
        float sc = exp2f(mrow[qi] - nm);    // 0 on first tile
        mrow[qi] = nm;
        lrow[qi] *= sc;
#pragma unroll
        for (int nf = 0; nf < 6; ++nf)
#pragma unroll
          for (int r = 0; r < 4; ++r) oacc[qi][nf][r] *= sc;
      }
      float m = mrow[qi], rs = 0.f;
#pragma unroll
      for (int kfr = 0; kfr < 4; ++kfr) {
        float p0 = exp2f(sacc[qi][kfr][0] - m);
        float p1 = exp2f(sacc[qi][kfr][1] - m);
        float p2 = exp2f(sacc[qi][kfr][2] - m);
        float p3 = exp2f(sacc[qi][kfr][3] - m);
        rs += (p0 + p1) + (p2 + p3);
        uint2v pk;
        pk[0] = cvt_pk_bf16(p0, p1);
        pk[1] = cvt_pk_bf16(p2, p3);
        *(uint2v*)&Pw[(qi * 16 + lc) * 72 + kfr * 16 + lr * 4] = pk;
      }
      rs += __shfl_xor(rs, 16);
      rs += __shfl_xor(rs, 32);
      lrow[qi] += rs;
    }
    asm volatile("s_waitcnt lgkmcnt(0)" ::: "memory");   // P visible (own wave)

    // O^T += V^T P^T, kchunk 0  (va wait: vmcnt(9) -- staging stays in flight)
    short8 pb0 = *(const short8*)&Pw[lc * 72 + lr * 8];
    short8 pb1 = *(const short8*)&Pw[(16 + lc) * 72 + lr * 8];
    __builtin_amdgcn_s_setprio(1);
#pragma unroll
    for (int nf = 0; nf < 6; ++nf) {
      oacc[0][nf] = mfma16(va[nf], pb0, oacc[0][nf]);
      oacc[1][nf] = mfma16(va[nf], pb1, oacc[1][nf]);
    }
    __builtin_amdgcn_s_setprio(0);

    // kchunk 1  (vc wait: vmcnt(3))
    pb0 = *(const short8*)&Pw[lc * 72 + 32 + lr * 8];
    pb1 = *(const short8*)&Pw[(16 + lc) * 72 + 32 + lr * 8];
    __builtin_amdgcn_s_setprio(1);
#pragma unroll
    for (int nf = 0; nf < 6; ++nf) {
      oacc[0][nf] = mfma16(vc[nf], pb0, oacc[0][nf]);
      oacc[1][nf] = mfma16(vc[nf], pb1, oacc[1][nf]);
    }
    __builtin_amdgcn_s_setprio(0);
    __syncthreads();   // staging (issued at tile top) long since landed
  }

  // epilogue: O^T -> O via per-wave LDS transpose, coalesced 16B stores
  u16* Cw = smem + w * 3328;                // [32][104]
  float inv[2] = {1.0f / lrow[0], 1.0f / lrow[1]};
#pragma unroll
  for (int qi = 0; qi < 2; ++qi) {
#pragma unroll
    for (int nf = 0; nf < 6; ++nf) {
      uint2v pk;
      pk[0] = cvt_pk_bf16(oacc[qi][nf][0] * inv[qi], oacc[qi][nf][1] * inv[qi]);
      pk[1] = cvt_pk_bf16(oacc[qi][nf][2] * inv[qi], oacc[qi][nf][3] * inv[qi]);
      *(uint2v*)&Cw[(qi * 16 + lc) * 104 + nf * 16 + lr * 4] = pk;
    }
  }
  asm volatile("s_waitcnt lgkmcnt(0)" ::: "memory");
  int crow0 = b * 1024 + qt * 128 + w * 32;
#pragma unroll
  for (int i = 0; i < 6; ++i) {
    int idx = i * 64 + l;                   // 32 rows x 12 chunks
    int row = idx / 12, c8 = idx % 12;
    short8 vv = *(const short8*)&Cw[row * 104 + c8 * 8];
    *(short8*)(ctx + (size_t)(crow0 + row) * 768 + h * 96 + c8 * 8) = vv;
  }
}

// ---------- launch ----------
extern "C" void kernel_launch(void* const* d_in, const int* in_sizes, int n_in,
                              void* d_out, int out_size, void* d_ws, size_t ws_size,
                              hipStream_t stream) {
  const float* x     = (const float*)d_in[0];
  const float* Wqkv  = (const float*)d_in[1];
  const float* bqkv  = (const float*)d_in[2];
  const float* Wproj = (const float*)d_in[3];
  const float* bproj = (const float*)d_in[4];
  float* out = (float*)d_out;

  char* ws = (char*)d_ws;
  u16*   xb     = (u16*)(ws);                    // 12,582,912 B (reused as ctx)
  u16*   wqkvT  = (u16*)(ws + 12582912);         //  3,538,944 B
  u16*   wprojT = (u16*)(ws + 16121856);         //  1,179,648 B
  float* bqkvp  = (float*)(ws + 17301504);       //      9,216 B
  u16*   qkvp   = (u16*)(ws + 17310720);         // 37,748,736 B (q,k cols only)
  u16*   vtb    = (u16*)(ws + 55059456);         // 12,582,912 B
  u16*   ctx    = xb;                            // xb dead after QKV GEMM

  k_cvt_x<<<6144, 256, 0, stream>>>(x, xb);
  k_tcvt<1><<<dim3(K3 / 32, Emb / 32), 256, 0, stream>>>(Wqkv, wqkvT, Emb, K3);
  k_tcvt<0><<<dim3(Emb / 32, Emb / 32), 256, 0, stream>>>(Wproj, wprojT, Emb, Emb);
  k_permbias<<<9, 256, 0, stream>>>(bqkv, bqkvp);
  k_gemm_bt<0><<<dim3(Mrows / 128, K3 / 128), 256, 0, stream>>>(
      xb, wqkvT, bqkvp, qkvp, vtb, nullptr, K3, Emb);
  k_attn<<<512, 256, 0, stream>>>(qkvp, vtb, ctx);
  k_gemm_bt<1><<<dim3(Mrows / 128, Emb / 128), 256, 0, stream>>>(
      ctx, wprojT, bproj, nullptr, nullptr, out, Emb, Emb);
}

// Round 11
// 132.980 us; speedup vs baseline: 1.4109x; 1.0018x over previous
//
#include <hip/hip_runtime.h>

typedef unsigned short u16;
typedef __attribute__((ext_vector_type(8))) short short8;   // 8 bf16 (guide §3 frag_ab)
typedef __attribute__((ext_vector_type(4))) short short4v;
typedef __attribute__((ext_vector_type(4))) float f32x4;    // frag_cd
typedef __attribute__((ext_vector_type(2))) unsigned int uint2v;

#define DEV static __device__ __forceinline__

static_assert(sizeof(short8) == 16, "short8 must be 16B");

// ---------- helpers ----------
DEV u16 f2b(float f) {                       // fp32 -> bf16, round-to-nearest-even
  union { float f; unsigned u; } a; a.f = f;
  unsigned u = a.u;
  unsigned r = (u + 0x7FFFu + ((u >> 16) & 1u)) >> 16;
  return (u16)r;
}

DEV unsigned cvt_pk_bf16(float lo, float hi) {   // {bf16(lo), bf16(hi)} packed
  unsigned r;
  asm("v_cvt_pk_bf16_f32 %0, %1, %2" : "=v"(r) : "v"(lo), "v"(hi));
  return r;
}

// MFMA via builtin: compiler manages hazards + allocates accumulators on the
// AGPR side of the gfx950 unified file (r5->r6 lesson: +18 us from this alone).
DEV f32x4 mfma16(short8 a, short8 b, f32x4 c) {
  return __builtin_amdgcn_mfma_f32_16x16x32_bf16(a, b, c, 0, 0, 0);
}

// async global->LDS, 16B per lane; LDS dest must be wave-uniform base + lane*16
DEV void gl_lds16(const u16* g, u16* l) {
  __builtin_amdgcn_global_load_lds(
      (const __attribute__((address_space(1))) void*)g,
      (__attribute__((address_space(3))) void*)l, 16, 0, 0);
}

// ---------- problem dims ----------
constexpr int Bz = 8, Nseq = 1024, Emb = 768, Hh = 8, Dh = 96;
constexpr int Mrows = Bz * Nseq;    // 8192
constexpr int K3 = 3 * Emb;         // 2304
// 768^-0.5 * log2(e): softmax done in exp2 domain (saves a mul per S element)
constexpr float QSCALE = 0.05205982021128899f;

// ---------- kernel 1: x fp32 -> bf16 ----------
__global__ __launch_bounds__(256) void k_cvt_x(const float* __restrict__ src,
                                               u16* __restrict__ dst) {
  int i = (blockIdx.x * 256 + threadIdx.x) * 4;
  float4 v = *(const float4*)(src + i);
  short4v o;
  o[0] = (short)f2b(v.x); o[1] = (short)f2b(v.y);
  o[2] = (short)f2b(v.z); o[3] = (short)f2b(v.w);
  *(short4v*)(dst + i) = o;
}

// ---------- kernel 2: transpose + cvt (+optional qkv column permutation) ----------
template <int PERM>
__global__ __launch_bounds__(256) void k_tcvt(const float* __restrict__ src,
                                              u16* __restrict__ dst, int R, int C) {
  __shared__ float t[32][33];
  int bx = blockIdx.x * 32;   // col tile in src
  int by = blockIdx.y * 32;   // row tile in src
  int c = threadIdx.x & 31, r8 = threadIdx.x >> 5;
#pragma unroll
  for (int p = 0; p < 4; ++p) {
    int r = r8 + p * 8;
    t[r][c] = src[(size_t)(by + r) * C + bx + c];
  }
  __syncthreads();
#pragma unroll
  for (int p = 0; p < 4; ++p) {
    int r = r8 + p * 8;
    int co = bx + r;           // dst row before permutation = src col
    int row = co;
    float mul = 1.f;
    if (PERM) {
      int h = co / 288, rem = co - h * 288;
      int d = rem / 3, s = rem - d * 3;
      row = s * 768 + h * 96 + d;
      if (s == 0) mul = QSCALE;
    }
    dst[(size_t)row * R + by + c] = f2b(t[c][r] * mul);
  }
}

// ---------- kernel 2b: permuted (and q-scaled) qkv bias, fp32 ----------
__global__ __launch_bounds__(256) void k_permbias(const float* __restrict__ b,
                                                  float* __restrict__ bp) {
  int co = blockIdx.x * 256 + threadIdx.x;
  if (co < 2304) {
    int h = co / 288, rem = co - h * 288, d = rem / 3, s = rem - d * 3;
    bp[s * 768 + h * 96 + d] = b[co] * (s == 0 ? QSCALE : 1.f);
  }
}

// ---------- kernel 3: GEMM  C[M][Nn] = A[M][K] * Bt[Nn][K]^T + bias ----------
// r9: T3/T4 pipeline — TRIPLE-buffered LDS staged 2 K-steps ahead; ONE barrier
// per step with counted s_waitcnt vmcnt(4) (never 0 mid-loop) so staging
// latency hides under MFMA of the 2 preceding steps. Cst aliased over the
// staging buffers (barrier-guarded) to stay under the 64KB static LDS limit.
// MODE 0: QKV gemm. cols<1536 -> LDS-transposed bf16 store to obf[.][2304];
//         cols>=1536 -> direct store into vT[B*H*96][1024].
// MODE 1: proj gemm, f32 direct store.
template <int MODE>
__global__ __launch_bounds__(256, 2) void k_gemm_bt(
    const u16* __restrict__ A, const u16* __restrict__ Bt,
    const float* __restrict__ bias,
    u16* __restrict__ obf, u16* __restrict__ vtb, float* __restrict__ of32,
    int Nn, int Kdim) {
  __shared__ __align__(16) u16 smem[24576];   // 49152 B: A0 A1 A2 B0 B1 B2
  int m0 = blockIdx.x * 128, n0 = blockIdx.y * 128;
  int tid = threadIdx.x;
  int w = tid >> 6, l = tid & 63, lr = l >> 4, lc = l & 15;
  int wr = w >> 1, wc = w & 1;
  f32x4 acc[4][4] = {};
  int nkt = Kdim >> 5;    // 24

  auto stage = [&](u16* bA, u16* bB, int t) {
#pragma unroll
    for (int i = 0; i < 2; ++i) {
      int idx = i * 256 + tid;              // 512 chunks of 16B per matrix
      int rr = idx >> 2, cc = (idx & 3) * 8;
      gl_lds16(A + (size_t)(m0 + rr) * Kdim + t * 32 + cc, bA + idx * 8);
      gl_lds16(Bt + (size_t)(n0 + rr) * Kdim + t * 32 + cc, bB + idx * 8);
    }
  };

  u16 *a0 = smem, *a1 = smem + 4096, *a2 = smem + 8192;
  u16 *b0 = smem + 12288, *b1 = smem + 16384, *b2 = smem + 20480;
  stage(a0, b0, 0);
  stage(a1, b1, 1);

  for (int kt = 0; kt < nkt; ++kt) {
    // tile kt staged 2 iterations ago -> counted wait, latency hidden.
    if (kt < nkt - 1)
      asm volatile("s_waitcnt vmcnt(4) lgkmcnt(0)\n\ts_barrier" ::: "memory");
    else
      asm volatile("s_waitcnt vmcnt(0) lgkmcnt(0)\n\ts_barrier" ::: "memory");
    if (kt + 2 < nkt) stage(a2, b2, kt + 2);   // overwrites tile kt-1's buffer
    short8 af[4];
#pragma unroll
    for (int mi = 0; mi < 4; ++mi)
      af[mi] = *(const short8*)&a0[(wr * 64 + mi * 16 + lc) * 32 + lr * 8];
#pragma unroll
    for (int ni = 0; ni < 4; ++ni) {
      short8 bf = *(const short8*)&b0[(wc * 64 + ni * 16 + lc) * 32 + lr * 8];
#pragma unroll
      for (int mi = 0; mi < 4; ++mi)
        acc[mi][ni] = mfma16(af[mi], bf, acc[mi][ni]);
    }
    u16* t;
    t = a0; a0 = a1; a1 = a2; a2 = t;
    t = b0; b0 = b1; b1 = b2; b2 = t;
  }
  __syncthreads();   // staging buffers dead; Cst aliases them below

  if (MODE == 0) {
    if (n0 < 1536) {
      // transposed store through per-wave LDS (coalesced 16B global stores)
      u16* Cb = smem + w * 2816;              // [32][88] per wave
#pragma unroll
      for (int mi2 = 0; mi2 < 2; ++mi2) {
#pragma unroll
        for (int mh = 0; mh < 2; ++mh) {
          int mi = mi2 * 2 + mh;
#pragma unroll
          for (int ni = 0; ni < 4; ++ni) {
            float bv = bias[n0 + wc * 64 + ni * 16 + lc];
#pragma unroll
            for (int r = 0; r < 4; ++r)
              Cb[(mh * 16 + lr * 4 + r) * 88 + ni * 16 + lc] =
                  f2b(acc[mi][ni][r] + bv);
          }
        }
#pragma unroll
        for (int i = 0; i < 4; ++i) {
          int idx = i * 64 + l;
          int row = idx >> 3, c8 = idx & 7;
          short8 vv = *(const short8*)&Cb[row * 88 + c8 * 8];
          int grow = m0 + wr * 64 + mi2 * 32 + row;
          int gcol = n0 + wc * 64 + c8 * 8;
          *(short8*)(obf + (size_t)grow * Nn + gcol) = vv;
        }
      }
    } else {
      // V section: write directly in vT layout [(b*8+h)*96+d][1024]
#pragma unroll
      for (int mi = 0; mi < 4; ++mi) {
#pragma unroll
        for (int ni = 0; ni < 4; ++ni) {
          int col = n0 + wc * 64 + ni * 16 + lc;
          float bv = bias[col];
          int dall = col - 1536;                       // = h*96 + d
          int row0 = m0 + wr * 64 + mi * 16 + lr * 4;  // rows 4-aligned, same b
          short4v o4;
#pragma unroll
          for (int r = 0; r < 4; ++r) o4[r] = (short)f2b(acc[mi][ni][r] + bv);
          *(short4v*)(vtb + ((size_t)(row0 >> 10) * 768 + dall) * 1024 +
                      (row0 & 1023)) = o4;
        }
      }
    }
  } else {
#pragma unroll
    for (int mi = 0; mi < 4; ++mi) {
#pragma unroll
      for (int ni = 0; ni < 4; ++ni) {
        int col = n0 + wc * 64 + ni * 16 + lc;
        float bv = bias[col];
        int row0 = m0 + wr * 64 + mi * 16 + lr * 4;
#pragma unroll
        for (int r = 0; r < 4; ++r)
          of32[(size_t)(row0 + r) * Nn + col] = acc[mi][ni][r] + bv;
      }
    }
  }
}

// ---------- kernel 4: flash attention (r9 = r6 geometry + vmem reorder) ----------
// block = (qt,h,b), b fastest (XCD L2 locality). 4 waves x 32 q rows.
// S^T = K·Q^T (lane holds a q-row's scores along k); PV as O^T = V^T·P^T.
// K double-buffered LDS via gl_lds. r9 FIX: per-tile vmem order is
// va, vc, THEN staging — so PV0 waits vmcnt(9), PV1 waits vmcnt(3), and the
// tile-end barrier's vmcnt(0) hits staging issued a full tile earlier.
// (r6 issued vc AFTER staging -> PV1's wait drained the staging queue every
// tile.) (256,2): grid = 2 blocks/CU, don't squeeze regs for unreachable occ.
__global__ __launch_bounds__(256, 2) void k_attn(const u16* __restrict__ qkvp,
                                                 const u16* __restrict__ vt,
                                                 u16* __restrict__ ctx) {
  __shared__ __align__(16) u16 smem[21504];   // Kb[2][64*96] | Pw[4][32*72]
  int blk = blockIdx.x;
  int b = blk & 7, h = (blk >> 3) & 7, qt = blk >> 6;
  int tid = threadIdx.x, w = tid >> 6, l = tid & 63;
  int lr = l >> 4, lc = l & 15;
  int q0 = qt * 128 + w * 32;
  const u16* qptr = qkvp + (size_t)b * 1024 * 2304 + h * 96;
  const u16* kptr = qptr + 768;
  const u16* vtp  = vt + (size_t)(b * 768 + h * 96) * 1024 +
                    (size_t)lc * 1024 + lr * 8;   // per-lane V base
  u16* Pw = smem + 12288 + w * 2304;          // [32][72]  (P stored [q][k])

  // K staging offsets (64 rows x 12 chunks of 8 u16 = 768 = 3 x 256)
  int soff[3], doff[3];
#pragma unroll
  for (int i = 0; i < 3; ++i) {
    int idx = i * 256 + tid;
    soff[i] = (idx / 12) * 2304 + (idx % 12) * 8;
    doff[i] = idx * 8;
  }

  // Q-frags (B-operand of swapped QK^T): Q[q0+16qi+lc][32kf+8lr+j]
  short8 qf[2][3];
#pragma unroll
  for (int qi = 0; qi < 2; ++qi)
#pragma unroll
    for (int kf = 0; kf < 3; ++kf)
      qf[qi][kf] = *(const short8*)(qptr + (size_t)(q0 + qi * 16 + lc) * 2304 +
                                    kf * 32 + lr * 8);

  float mrow[2] = {-INFINITY, -INFINITY}, lrow[2] = {0.f, 0.f};
  f32x4 oacc[2][6] = {};    // O^T[d=16nf+4lr+r][q=16qi+lc]

  // prologue: stage K tile 0
#pragma unroll
  for (int i = 0; i < 3; ++i) gl_lds16(kptr + soff[i], smem + doff[i]);
  __syncthreads();

  for (int kt = 0; kt < 16; ++kt) {
    const u16* Kc = smem + (kt & 1) * 6144;
    const u16* vkt = vtp + kt * 64;

    // ALL of this tile's V frags issue first (before staging) so their
    // vmcnt waits (9 / 3) never drain the staging queue.
    short8 va[6], vc[6];
#pragma unroll
    for (int nf = 0; nf < 6; ++nf) {
      va[nf] = *(const short8*)(vkt + (size_t)nf * 16384);
      vc[nf] = *(const short8*)(vkt + (size_t)nf * 16384 + 32);
    }
    asm volatile("" ::: "memory");         // pin staging after the V loads

    if (kt < 15) {                          // async-stage next K tile
      const u16* kg = kptr + (size_t)(kt + 1) * 64 * 2304;
      u16* db = smem + ((kt + 1) & 1) * 6144;
#pragma unroll
      for (int i = 0; i < 3; ++i) gl_lds16(kg + soff[i], db + doff[i]);
    }

    // S^T = K Q^T : sacc[qi][kfr] holds S^T[k=16kfr+4lr+r][q=16qi+lc]
    f32x4 sacc[2][4] = {};
    __builtin_amdgcn_s_setprio(1);
#pragma unroll
    for (int kfr = 0; kfr < 4; ++kfr) {
#pragma unroll
      for (int kf = 0; kf < 3; ++kf) {
        short8 kb = *(const short8*)&Kc[(kfr * 16 + lc) * 96 + kf * 32 + lr * 8];
        sacc[0][kfr] = mfma16(kb, qf[0][kf], sacc[0][kfr]);
        sacc[1][kfr] = mfma16(kb, qf[1][kf], sacc[1][kfr]);
      }
    }
    __builtin_amdgcn_s_setprio(0);

    // online softmax (exp2 domain, deferred max THR=8), mostly in-lane
#pragma unroll
    for (int qi = 0; qi < 2; ++qi) {
      float mx = sacc[qi][0][0];
#pragma unroll
      for (int kfr = 0; kfr < 4; ++kfr)
#pragma unroll
        for (int r = 0; r < 4; ++r)
          if (kfr | r) mx = fmaxf(mx, sacc[qi][kfr][r]);
      mx = fmaxf(mx, __shfl_xor(mx, 16));
      mx = fmaxf(mx, __shfl_xor(mx, 32));
      if (__any(mx > mrow[qi] + 8.f)) {     // wave-uniform, rare after tile 0
        float nm = fmaxf(mrow[qi], mx);
        float sc = exp2f(mrow[qi] - nm);    // 0 on first tile
        mrow[qi] = nm;
        lrow[qi] *= sc;
#pragma unroll
        for (int nf = 0; nf < 6; ++nf)
#pragma unroll
          for (int r = 0; r < 4; ++r) oacc[qi][nf][r] *= sc;
      }
      float m = mrow[qi], rs = 0.f;
#pragma unroll
      for (int kfr = 0; kfr < 4; ++kfr) {
        float p0 = exp2f(sacc[qi][kfr][0] - m);
        float p1 = exp2f(sacc[qi][kfr][1] - m);
        float p2 = exp2f(sacc[qi][kfr][2] - m);
        float p3 = exp2f(sacc[qi][kfr][3] - m);
        rs += (p0 + p1) + (p2 + p3);
        uint2v pk;
        pk[0] = cvt_pk_bf16(p0, p1);
        pk[1] = cvt_pk_bf16(p2, p3);
        *(uint2v*)&Pw[(qi * 16 + lc) * 72 + kfr * 16 + lr * 4] = pk;
      }
      rs += __shfl_xor(rs, 16);
      rs += __shfl_xor(rs, 32);
      lrow[qi] += rs;
    }
    asm volatile("s_waitcnt lgkmcnt(0)" ::: "memory");   // P visible (own wave)

    // O^T += V^T P^T, kchunk 0  (va wait: vmcnt(9) -- staging stays in flight)
    short8 pb0 = *(const short8*)&Pw[lc * 72 + lr * 8];
    short8 pb1 = *(const short8*)&Pw[(16 + lc) * 72 + lr * 8];
    __builtin_amdgcn_s_setprio(1);
#pragma unroll
    for (int nf = 0; nf < 6; ++nf) {
      oacc[0][nf] = mfma16(va[nf], pb0, oacc[0][nf]);
      oacc[1][nf] = mfma16(va[nf], pb1, oacc[1][nf]);
    }
    __builtin_amdgcn_s_setprio(0);

    // kchunk 1  (vc wait: vmcnt(3))
    pb0 = *(const short8*)&Pw[lc * 72 + 32 + lr * 8];
    pb1 = *(const short8*)&Pw[(16 + lc) * 72 + 32 + lr * 8];
    __builtin_amdgcn_s_setprio(1);
#pragma unroll
    for (int nf = 0; nf < 6; ++nf) {
      oacc[0][nf] = mfma16(vc[nf], pb0, oacc[0][nf]);
      oacc[1][nf] = mfma16(vc[nf], pb1, oacc[1][nf]);
    }
    __builtin_amdgcn_s_setprio(0);
    __syncthreads();   // staging (issued at tile top) long since landed
  }

  // epilogue: O^T -> O via per-wave LDS transpose, coalesced 16B stores
  u16* Cw = smem + w * 3328;                // [32][104]
  float inv[2] = {1.0f / lrow[0], 1.0f / lrow[1]};
#pragma unroll
  for (int qi = 0; qi < 2; ++qi) {
#pragma unroll
    for (int nf = 0; nf < 6; ++nf) {
      uint2v pk;
      pk[0] = cvt_pk_bf16(oacc[qi][nf][0] * inv[qi], oacc[qi][nf][1] * inv[qi]);
      pk[1] = cvt_pk_bf16(oacc[qi][nf][2] * inv[qi], oacc[qi][nf][3] * inv[qi]);
      *(uint2v*)&Cw[(qi * 16 + lc) * 104 + nf * 16 + lr * 4] = pk;
    }
  }
  asm volatile("s_waitcnt lgkmcnt(0)" ::: "memory");
  int crow0 = b * 1024 + qt * 128 + w * 32;
#pragma unroll
  for (int i = 0; i < 6; ++i) {
    int idx = i * 64 + l;                   // 32 rows x 12 chunks
    int row = idx / 12, c8 = idx % 12;
    short8 vv = *(const short8*)&Cw[row * 104 + c8 * 8];
    *(short8*)(ctx + (size_t)(crow0 + row) * 768 + h * 96 + c8 * 8) = vv;
  }
}

// ---------- launch ----------
extern "C" void kernel_launch(void* const* d_in, const int* in_sizes, int n_in,
                              void* d_out, int out_size, void* d_ws, size_t ws_size,
                              hipStream_t stream) {
  const float* x     = (const float*)d_in[0];
  const float* Wqkv  = (const float*)d_in[1];
  const float* bqkv  = (const float*)d_in[2];
  const float* Wproj = (const float*)d_in[3];
  const float* bproj = (const float*)d_in[4];
  float* out = (float*)d_out;

  char* ws = (char*)d_ws;
  u16*   xb     = (u16*)(ws);                    // 12,582,912 B (reused as ctx)
  u16*   wqkvT  = (u16*)(ws + 12582912);         //  3,538,944 B
  u16*   wprojT = (u16*)(ws + 16121856);         //  1,179,648 B
  float* bqkvp  = (float*)(ws + 17301504);       //      9,216 B
  u16*   qkvp   = (u16*)(ws + 17310720);         // 37,748,736 B (q,k cols only)
  u16*   vtb    = (u16*)(ws + 55059456);         // 12,582,912 B
  u16*   ctx    = xb;                            // xb dead after QKV GEMM

  k_cvt_x<<<6144, 256, 0, stream>>>(x, xb);
  k_tcvt<1><<<dim3(K3 / 32, Emb / 32), 256, 0, stream>>>(Wqkv, wqkvT, Emb, K3);
  k_tcvt<0><<<dim3(Emb / 32, Emb / 32), 256, 0, stream>>>(Wproj, wprojT, Emb, Emb);
  k_permbias<<<9, 256, 0, stream>>>(bqkv, bqkvp);
  k_gemm_bt<0><<<dim3(Mrows / 128, K3 / 128), 256, 0, stream>>>(
      xb, wqkvT, bqkvp, qkvp, vtb, nullptr, K3, Emb);
  k_attn<<<512, 256, 0, stream>>>(qkvp, vtb, ctx);
  k_gemm_bt<1><<<dim3(Mrows / 128, Emb / 128), 256, 0, stream>>>(
      ctx, wprojT, bproj, nullptr, nullptr, out, Emb, Emb);
}

// Round 12
// 132.946 us; speedup vs baseline: 1.4112x; 1.0003x over previous
//
#include <hip/hip_runtime.h>

typedef unsigned short u16;
typedef __attribute__((ext_vector_type(8))) short short8;   // 8 bf16 (guide §3 frag_ab)
typedef __attribute__((ext_vector_type(4))) short short4v;
typedef __attribute__((ext_vector_type(4))) float f32x4;    // frag_cd
typedef __attribute__((ext_vector_type(2))) unsigned int uint2v;

#define DEV static __device__ __forceinline__

static_assert(sizeof(short8) == 16, "short8 must be 16B");

// ---------- helpers ----------
DEV u16 f2b(float f) {                       // fp32 -> bf16, round-to-nearest-even
  union { float f; unsigned u; } a; a.f = f;
  unsigned u = a.u;
  unsigned r = (u + 0x7FFFu + ((u >> 16) & 1u)) >> 16;
  return (u16)r;
}

DEV unsigned cvt_pk_bf16(float lo, float hi) {   // {bf16(lo), bf16(hi)} packed
  unsigned r;
  asm("v_cvt_pk_bf16_f32 %0, %1, %2" : "=v"(r) : "v"(lo), "v"(hi));
  return r;
}

// MFMA via builtin: compiler manages hazards + allocates accumulators on the
// AGPR side of the gfx950 unified file (r5->r6 lesson: +18 us from this alone).
DEV f32x4 mfma16(short8 a, short8 b, f32x4 c) {
  return __builtin_amdgcn_mfma_f32_16x16x32_bf16(a, b, c, 0, 0, 0);
}

// async global->LDS, 16B per lane; LDS dest must be wave-uniform base + lane*16
DEV void gl_lds16(const u16* g, u16* l) {
  __builtin_amdgcn_global_load_lds(
      (const __attribute__((address_space(1))) void*)g,
      (__attribute__((address_space(3))) void*)l, 16, 0, 0);
}

// ---------- problem dims ----------
constexpr int Bz = 8, Nseq = 1024, Emb = 768, Hh = 8, Dh = 96;
constexpr int Mrows = Bz * Nseq;    // 8192
constexpr int K3 = 3 * Emb;         // 2304
// 768^-0.5 * log2(e): softmax done in exp2 domain (saves a mul per S element)
constexpr float QSCALE = 0.05205982021128899f;

// ---------- kernel 1: x fp32 -> bf16 ----------
__global__ __launch_bounds__(256) void k_cvt_x(const float* __restrict__ src,
                                               u16* __restrict__ dst) {
  int i = (blockIdx.x * 256 + threadIdx.x) * 4;
  float4 v = *(const float4*)(src + i);
  short4v o;
  o[0] = (short)f2b(v.x); o[1] = (short)f2b(v.y);
  o[2] = (short)f2b(v.z); o[3] = (short)f2b(v.w);
  *(short4v*)(dst + i) = o;
}

// ---------- kernel 2: transpose + cvt (+optional qkv column permutation) ----------
template <int PERM>
__global__ __launch_bounds__(256) void k_tcvt(const float* __restrict__ src,
                                              u16* __restrict__ dst, int R, int C) {
  __shared__ float t[32][33];
  int bx = blockIdx.x * 32;   // col tile in src
  int by = blockIdx.y * 32;   // row tile in src
  int c = threadIdx.x & 31, r8 = threadIdx.x >> 5;
#pragma unroll
  for (int p = 0; p < 4; ++p) {
    int r = r8 + p * 8;
    t[r][c] = src[(size_t)(by + r) * C + bx + c];
  }
  __syncthreads();
#pragma unroll
  for (int p = 0; p < 4; ++p) {
    int r = r8 + p * 8;
    int co = bx + r;           // dst row before permutation = src col
    int row = co;
    float mul = 1.f;
    if (PERM) {
      int h = co / 288, rem = co - h * 288;
      int d = rem / 3, s = rem - d * 3;
      row = s * 768 + h * 96 + d;
      if (s == 0) mul = QSCALE;
    }
    dst[(size_t)row * R + by + c] = f2b(t[c][r] * mul);
  }
}

// ---------- kernel 2b: permuted (and q-scaled) qkv bias, fp32 ----------
__global__ __launch_bounds__(256) void k_permbias(const float* __restrict__ b,
                                                  float* __restrict__ bp) {
  int co = blockIdx.x * 256 + threadIdx.x;
  if (co < 2304) {
    int h = co / 288, rem = co - h * 288, d = rem / 3, s = rem - d * 3;
    bp[s * 768 + h * 96 + d] = b[co] * (s == 0 ? QSCALE : 1.f);
  }
}

// ---------- kernel 3: GEMM  C[M][Nn] = A[M][K] * Bt[Nn][K]^T + bias ----------
// r9: T3/T4 pipeline — TRIPLE-buffered LDS staged 2 K-steps ahead; ONE barrier
// per step with counted s_waitcnt vmcnt(4) (never 0 mid-loop) so staging
// latency hides under MFMA of the 2 preceding steps. Cst aliased over the
// staging buffers (barrier-guarded) to stay under the 64KB static LDS limit.
// MODE 0: QKV gemm. cols<1536 -> LDS-transposed bf16 store to obf[.][2304];
//         cols>=1536 -> direct store into vT[B*H*96][1024].
// MODE 1: proj gemm, f32 direct store.
template <int MODE>
__global__ __launch_bounds__(256, 2) void k_gemm_bt(
    const u16* __restrict__ A, const u16* __restrict__ Bt,
    const float* __restrict__ bias,
    u16* __restrict__ obf, u16* __restrict__ vtb, float* __restrict__ of32,
    int Nn, int Kdim) {
  __shared__ __align__(16) u16 smem[24576];   // 49152 B: A0 A1 A2 B0 B1 B2
  int m0 = blockIdx.x * 128, n0 = blockIdx.y * 128;
  int tid = threadIdx.x;
  int w = tid >> 6, l = tid & 63, lr = l >> 4, lc = l & 15;
  int wr = w >> 1, wc = w & 1;
  f32x4 acc[4][4] = {};
  int nkt = Kdim >> 5;    // 24

  auto stage = [&](u16* bA, u16* bB, int t) {
#pragma unroll
    for (int i = 0; i < 2; ++i) {
      int idx = i * 256 + tid;              // 512 chunks of 16B per matrix
      int rr = idx >> 2, cc = (idx & 3) * 8;
      gl_lds16(A + (size_t)(m0 + rr) * Kdim + t * 32 + cc, bA + idx * 8);
      gl_lds16(Bt + (size_t)(n0 + rr) * Kdim + t * 32 + cc, bB + idx * 8);
    }
  };

  u16 *a0 = smem, *a1 = smem + 4096, *a2 = smem + 8192;
  u16 *b0 = smem + 12288, *b1 = smem + 16384, *b2 = smem + 20480;
  stage(a0, b0, 0);
  stage(a1, b1, 1);

  for (int kt = 0; kt < nkt; ++kt) {
    // tile kt staged 2 iterations ago -> counted wait, latency hidden.
    if (kt < nkt - 1)
      asm volatile("s_waitcnt vmcnt(4) lgkmcnt(0)\n\ts_barrier" ::: "memory");
    else
      asm volatile("s_waitcnt vmcnt(0) lgkmcnt(0)\n\ts_barrier" ::: "memory");
    if (kt + 2 < nkt) stage(a2, b2, kt + 2);   // overwrites tile kt-1's buffer
    short8 af[4];
#pragma unroll
    for (int mi = 0; mi < 4; ++mi)
      af[mi] = *(const short8*)&a0[(wr * 64 + mi * 16 + lc) * 32 + lr * 8];
#pragma unroll
    for (int ni = 0; ni < 4; ++ni) {
      short8 bf = *(const short8*)&b0[(wc * 64 + ni * 16 + lc) * 32 + lr * 8];
#pragma unroll
      for (int mi = 0; mi < 4; ++mi)
        acc[mi][ni] = mfma16(af[mi], bf, acc[mi][ni]);
    }
    u16* t;
    t = a0; a0 = a1; a1 = a2; a2 = t;
    t = b0; b0 = b1; b1 = b2; b2 = t;
  }
  __syncthreads();   // staging buffers dead; Cst aliases them below

  if (MODE == 0) {
    if (n0 < 1536) {
      // transposed store through per-wave LDS (coalesced 16B global stores)
      u16* Cb = smem + w * 2816;              // [32][88] per wave
#pragma unroll
      for (int mi2 = 0; mi2 < 2; ++mi2) {
#pragma unroll
        for (int mh = 0; mh < 2; ++mh) {
          int mi = mi2 * 2 + mh;
#pragma unroll
          for (int ni = 0; ni < 4; ++ni) {
            float bv = bias[n0 + wc * 64 + ni * 16 + lc];
#pragma unroll
            for (int r = 0; r < 4; ++r)
              Cb[(mh * 16 + lr * 4 + r) * 88 + ni * 16 + lc] =
                  f2b(acc[mi][ni][r] + bv);
          }
        }
#pragma unroll
        for (int i = 0; i < 4; ++i) {
          int idx = i * 64 + l;
          int row = idx >> 3, c8 = idx & 7;
          short8 vv = *(const short8*)&Cb[row * 88 + c8 * 8];
          int grow = m0 + wr * 64 + mi2 * 32 + row;
          int gcol = n0 + wc * 64 + c8 * 8;
          *(short8*)(obf + (size_t)grow * Nn + gcol) = vv;
        }
      }
    } else {
      // V section: write directly in vT layout [(b*8+h)*96+d][1024]
#pragma unroll
      for (int mi = 0; mi < 4; ++mi) {
#pragma unroll
        for (int ni = 0; ni < 4; ++ni) {
          int col = n0 + wc * 64 + ni * 16 + lc;
          float bv = bias[col];
          int dall = col - 1536;                       // = h*96 + d
          int row0 = m0 + wr * 64 + mi * 16 + lr * 4;  // rows 4-aligned, same b
          short4v o4;
#pragma unroll
          for (int r = 0; r < 4; ++r) o4[r] = (short)f2b(acc[mi][ni][r] + bv);
          *(short4v*)(vtb + ((size_t)(row0 >> 10) * 768 + dall) * 1024 +
                      (row0 & 1023)) = o4;
        }
      }
    }
  } else {
#pragma unroll
    for (int mi = 0; mi < 4; ++mi) {
#pragma unroll
      for (int ni = 0; ni < 4; ++ni) {
        int col = n0 + wc * 64 + ni * 16 + lc;
        float bv = bias[col];
        int row0 = m0 + wr * 64 + mi * 16 + lr * 4;
#pragma unroll
        for (int r = 0; r < 4; ++r)
          of32[(size_t)(row0 + r) * Nn + col] = acc[mi][ni][r] + bv;
      }
    }
  }
}

// ---------- kernel 4: flash attention (r9 = r6 geometry + vmem reorder) ----------
// block = (qt,h,b), b fastest (XCD L2 locality). 4 waves x 32 q rows.
// S^T = K·Q^T (lane holds a q-row's scores along k); PV as O^T = V^T·P^T.
// K double-buffered LDS via gl_lds. r9 FIX: per-tile vmem order is
// va, vc, THEN staging — so PV0 waits vmcnt(9), PV1 waits vmcnt(3), and the
// tile-end barrier's vmcnt(0) hits staging issued a full tile earlier.
// (r6 issued vc AFTER staging -> PV1's wait drained the staging queue every
// tile.) (256,2): grid = 2 blocks/CU, don't squeeze regs for unreachable occ.
__global__ __launch_bounds__(256, 2) void k_attn(const u16* __restrict__ qkvp,
                                                 const u16* __restrict__ vt,
                                                 u16* __restrict__ ctx) {
  __shared__ __align__(16) u16 smem[21504];   // Kb[2][64*96] | Pw[4][32*72]
  int blk = blockIdx.x;
  int b = blk & 7, h = (blk >> 3) & 7, qt = blk >> 6;
  int tid = threadIdx.x, w = tid >> 6, l = tid & 63;
  int lr = l >> 4, lc = l & 15;
  int q0 = qt * 128 + w * 32;
  const u16* qptr = qkvp + (size_t)b * 1024 * 2304 + h * 96;
  const u16* kptr = qptr + 768;
  const u16* vtp  = vt + (size_t)(b * 768 + h * 96) * 1024 +
                    (size_t)lc * 1024 + lr * 8;   // per-lane V base
  u16* Pw = smem + 12288 + w * 2304;          // [32][72]  (P stored [q][k])

  // K staging offsets (64 rows x 12 chunks of 8 u16 = 768 = 3 x 256)
  int soff[3], doff[3];
#pragma unroll
  for (int i = 0; i < 3; ++i) {
    int idx = i * 256 + tid;
    soff[i] = (idx / 12) * 2304 + (idx % 12) * 8;
    doff[i] = idx * 8;
  }

  // Q-frags (B-operand of swapped QK^T): Q[q0+16qi+lc][32kf+8lr+j]
  short8 qf[2][3];
#pragma unroll
  for (int qi = 0; qi < 2; ++qi)
#pragma unroll
    for (int kf = 0; kf < 3; ++kf)
      qf[qi][kf] = *(const short8*)(qptr + (size_t)(q0 + qi * 16 + lc) * 2304 +
                                    kf * 32 + lr * 8);

  float mrow[2] = {-INFINITY, -INFINITY}, lrow[2] = {0.f, 0.f};
  f32x4 oacc[2][6] = {};    // O^T[d=16nf+4lr+r][q=16qi+lc]

  // prologue: stage K tile 0
#pragma unroll
  for (int i = 0; i < 3; ++i) gl_lds16(kptr + soff[i], smem + doff[i]);
  __syncthreads();

  for (int kt = 0; kt < 16; ++kt) {
    const u16* Kc = smem + (kt & 1) * 6144;
    const u16* vkt = vtp + kt * 64;

    // ALL of this tile's V frags issue first (before staging) so their
    // vmcnt waits (9 / 3) never drain the staging queue.
    short8 va[6], vc[6];
#pragma unroll
    for (int nf = 0; nf < 6; ++nf) {
      va[nf] = *(const short8*)(vkt + (size_t)nf * 16384);
      vc[nf] = *(const short8*)(vkt + (size_t)nf * 16384 + 32);
    }
    asm volatile("" ::: "memory");         // pin staging after the V loads

    if (kt < 15) {                          // async-stage next K tile
      const u16* kg = kptr + (size_t)(kt + 1) * 64 * 2304;
      u16* db = smem + ((kt + 1) & 1) * 6144;
#pragma unroll
      for (int i = 0; i < 3; ++i) gl_lds16(kg + soff[i], db + doff[i]);
    }

    // S^T = K Q^T : sacc[qi][kfr] holds S^T[k=16kfr+4lr+r][q=16qi+lc]
    f32x4 sacc[2][4] = {};
    __builtin_amdgcn_s_setprio(1);
#pragma unroll
    for (int kfr = 0; kfr < 4; ++kfr) {
#pragma unroll
      for (int kf = 0; kf < 3; ++kf) {
        short8 kb = *(const short8*)&Kc[(kfr * 16 + lc) * 96 + kf * 32 + lr * 8];
        sacc[0][kfr] = mfma16(kb, qf[0][kf], sacc[0][kfr]);
        sacc[1][kfr] = mfma16(kb, qf[1][kf], sacc[1][kfr]);
      }
    }
    __builtin_amdgcn_s_setprio(0);

    // online softmax (exp2 domain, deferred max THR=8), mostly in-lane
#pragma unroll
    for (int qi = 0; qi < 2; ++qi) {
      float mx = sacc[qi][0][0];
#pragma unroll
      for (int kfr = 0; kfr < 4; ++kfr)
#pragma unroll
        for (int r = 0; r < 4; ++r)
          if (kfr | r) mx = fmaxf(mx, sacc[qi][kfr][r]);
      mx = fmaxf(mx, __shfl_xor(mx, 16));
      mx = fmaxf(mx, __shfl_xor(mx, 32));
      if (__any(mx > mrow[qi] + 8.f)) {     // wave-uniform, rare after tile 0
        float nm = fmaxf(mrow[qi], mx);
        float sc = exp2f(mrow[qi] - nm);    // 0 on first tile
        mrow[qi] = nm;
        lrow[qi] *= sc;
#pragma unroll
        for (int nf = 0; nf < 6; ++nf)
#pragma unroll
          for (int r = 0; r < 4; ++r) oacc[qi][nf][r] *= sc;
      }
      float m = mrow[qi], rs = 0.f;
#pragma unroll
      for (int kfr = 0; kfr < 4; ++kfr) {
        float p0 = exp2f(sacc[qi][kfr][0] - m);
        float p1 = exp2f(sacc[qi][kfr][1] - m);
        float p2 = exp2f(sacc[qi][kfr][2] - m);
        float p3 = exp2f(sacc[qi][kfr][3] - m);
        rs += (p0 + p1) + (p2 + p3);
        uint2v pk;
        pk[0] = cvt_pk_bf16(p0, p1);
        pk[1] = cvt_pk_bf16(p2, p3);
        *(uint2v*)&Pw[(qi * 16 + lc) * 72 + kfr * 16 + lr * 4] = pk;
      }
      rs += __shfl_xor(rs, 16);
      rs += __shfl_xor(rs, 32);
      lrow[qi] += rs;
    }
    asm volatile("s_waitcnt lgkmcnt(0)" ::: "memory");   // P visible (own wave)

    // O^T += V^T P^T, kchunk 0  (va wait: vmcnt(9) -- staging stays in flight)
    short8 pb0 = *(const short8*)&Pw[lc * 72 + lr * 8];
    short8 pb1 = *(const short8*)&Pw[(16 + lc) * 72 + lr * 8];
    __builtin_amdgcn_s_setprio(1);
#pragma unroll
    for (int nf = 0; nf < 6; ++nf) {
      oacc[0][nf] = mfma16(va[nf], pb0, oacc[0][nf]);
      oacc[1][nf] = mfma16(va[nf], pb1, oacc[1][nf]);
    }
    __builtin_amdgcn_s_setprio(0);

    // kchunk 1  (vc wait: vmcnt(3))
    pb0 = *(const short8*)&Pw[lc * 72 + 32 + lr * 8];
    pb1 = *(const short8*)&Pw[(16 + lc) * 72 + 32 + lr * 8];
    __builtin_amdgcn_s_setprio(1);
#pragma unroll
    for (int nf = 0; nf < 6; ++nf) {
      oacc[0][nf] = mfma16(vc[nf], pb0, oacc[0][nf]);
      oacc[1][nf] = mfma16(vc[nf], pb1, oacc[1][nf]);
    }
    __builtin_amdgcn_s_setprio(0);
    __syncthreads();   // staging (issued at tile top) long since landed
  }

  // epilogue: O^T -> O via per-wave LDS transpose, coalesced 16B stores
  u16* Cw = smem + w * 3328;                // [32][104]
  float inv[2] = {1.0f / lrow[0], 1.0f / lrow[1]};
#pragma unroll
  for (int qi = 0; qi < 2; ++qi) {
#pragma unroll
    for (int nf = 0; nf < 6; ++nf) {
      uint2v pk;
      pk[0] = cvt_pk_bf16(oacc[qi][nf][0] * inv[qi], oacc[qi][nf][1] * inv[qi]);
      pk[1] = cvt_pk_bf16(oacc[qi][nf][2] * inv[qi], oacc[qi][nf][3] * inv[qi]);
      *(uint2v*)&Cw[(qi * 16 + lc) * 104 + nf * 16 + lr * 4] = pk;
    }
  }
  asm volatile("s_waitcnt lgkmcnt(0)" ::: "memory");
  int crow0 = b * 1024 + qt * 128 + w * 32;
#pragma unroll
  for (int i = 0; i < 6; ++i) {
    int idx = i * 64 + l;                   // 32 rows x 12 chunks
    int row = idx / 12, c8 = idx % 12;
    short8 vv = *(const short8*)&Cw[row * 104 + c8 * 8];
    *(short8*)(ctx + (size_t)(crow0 + row) * 768 + h * 96 + c8 * 8) = vv;
  }
}

// ---------- launch ----------
extern "C" void kernel_launch(void* const* d_in, const int* in_sizes, int n_in,
                              void* d_out, int out_size, void* d_ws, size_t ws_size,
                              hipStream_t stream) {
  const float* x     = (const float*)d_in[0];
  const float* Wqkv  = (const float*)d_in[1];
  const float* bqkv  = (const float*)d_in[2];
  const float* Wproj = (const float*)d_in[3];
  const float* bproj = (const float*)d_in[4];
  float* out = (float*)d_out;

  char* ws = (char*)d_ws;
  u16*   xb     = (u16*)(ws);                    // 12,582,912 B (reused as ctx)
  u16*   wqkvT  = (u16*)(ws + 12582912);         //  3,538,944 B
  u16*   wprojT = (u16*)(ws + 16121856);         //  1,179,648 B
  float* bqkvp  = (float*)(ws + 17301504);       //      9,216 B
  u16*   qkvp   = (u16*)(ws + 17310720);         // 37,748,736 B (q,k cols only)
  u16*   vtb    = (u16*)(ws + 55059456);         // 12,582,912 B
  u16*   ctx    = xb;                            // xb dead after QKV GEMM

  k_cvt_x<<<6144, 256, 0, stream>>>(x, xb);
  k_tcvt<1><<<dim3(K3 / 32, Emb / 32), 256, 0, stream>>>(Wqkv, wqkvT, Emb, K3);
  k_tcvt<0><<<dim3(Emb / 32, Emb / 32), 256, 0, stream>>>(Wproj, wprojT, Emb, Emb);
  k_permbias<<<9, 256, 0, stream>>>(bqkv, bqkvp);
  k_gemm_bt<0><<<dim3(Mrows / 128, K3 / 128), 256, 0, stream>>>(
      xb, wqkvT, bqkvp, qkvp, vtb, nullptr, K3, Emb);
  k_attn<<<512, 256, 0, stream>>>(qkvp, vtb, ctx);
  k_gemm_bt<1><<<dim3(Mrows / 128, Emb / 128), 256, 0, stream>>>(
      ctx, wprojT, bproj, nullptr, nullptr, out, Emb, Emb);
}